// Round 3
// baseline (7286.645 us; speedup 1.0000x reference)
//
#include <hip/hip_runtime.h>
#include <cstdio>
#include <cstdint>

// ---------------- constants ----------------
#define BB 8
#define LSQ 1024
#define LDQ 512
#define DD 512
#define HH 8
#define EE 64
#define UU 35   // = 5*ceil(ln(1024)) = 5*ceil(ln(512)) = top-k u and sample count

// ---------------- threefry2x32 (JAX-compatible) ----------------
__host__ __device__ inline unsigned rotl32(unsigned x, int r){ return (x<<r)|(x>>(32-r)); }

__host__ __device__ inline void tf2x32(unsigned k0, unsigned k1, unsigned x0, unsigned x1,
                                       unsigned &o0, unsigned &o1){
  unsigned ks2 = k0 ^ k1 ^ 0x1BD11BDAu;
#define TF_RND(rr) { x0 += x1; x1 = rotl32(x1, rr); x1 ^= x0; }
  x0 += k0; x1 += k1;
  TF_RND(13) TF_RND(15) TF_RND(26) TF_RND(6)
  x0 += k1; x1 += ks2 + 1u;
  TF_RND(17) TF_RND(29) TF_RND(16) TF_RND(24)
  x0 += ks2; x1 += k0 + 2u;
  TF_RND(13) TF_RND(15) TF_RND(26) TF_RND(6)
  x0 += k0; x1 += k1 + 3u;
  TF_RND(17) TF_RND(29) TF_RND(16) TF_RND(24)
  x0 += k1; x1 += ks2 + 4u;
  TF_RND(13) TF_RND(15) TF_RND(26) TF_RND(6)
  x0 += ks2; x1 += k0 + 5u;
#undef TF_RND
  o0 = x0; o1 = x1;
}

// idx = random_bits(k2)[i] % Lk  (threefry_partitionable=True path:
// bits[i] = w0 ^ w1 of block(k2, hi(i64)=0, lo(i64)=i); Lk is pow2 so the
// randint double-width correction vanishes (2^16 % Lk == 0)).
// FALLBACK (if absmax small-but-failing): legacy scheme — split uses
// tf2x32(key, 1, 3) for the lower key and bits[i] pairs (i, i+n/2).
__global__ void idx_kernel(unsigned k2a, unsigned k2b, int* __restrict__ idx, int n, int lkMask){
  int i = blockIdx.x*blockDim.x + threadIdx.x;
  if (i >= n) return;
  unsigned o0,o1; tf2x32(k2a, k2b, 0u, (unsigned)i, o0, o1);
  idx[i] = (int)((o0 ^ o1) & (unsigned)lkMask);
}

// ---------------- token conv (wrap pad) + positional embedding ----------------
__global__ __launch_bounds__(512) void embed_kernel(const float* __restrict__ x,
    const float* __restrict__ W, const float* __restrict__ bias,
    float* __restrict__ out, int L){
  int bl = blockIdx.x; int b = bl / L; int l = bl - b*L;
  int d = threadIdx.x;
  __shared__ float xs[3][16];
  if (d < 48){
    int t = d / 16, c = d - t*16;
    int ll = l + t - 1; ll = (ll + L) % L;
    xs[t][c] = x[((size_t)b*L + ll)*16 + c];
  }
  __syncthreads();
  float acc = bias[d];
  const float* w = W + (size_t)d*48;   // W[d][c][t]
  #pragma unroll
  for (int c=0;c<16;c++){
    acc += xs[0][c]*w[c*3+0] + xs[1][c]*w[c*3+1] + xs[2][c]*w[c*3+2];
  }
  // positional embedding
  int p2 = (d >> 1) * 2;
  float freq = expf((float)p2 * (-(logf(10000.0f)/512.0f)));
  float ang = (float)l * freq;
  acc += (d & 1) ? cosf(ang) : sinf(ang);
  out[((size_t)b*L + l)*DD + d] = acc;
}

// ---------------- generic GEMM: C = A(MxK) * W(NxK)^T + bias ----------------
// epi: 0 = plain, 1 = exact GELU, 2 = head-split write (B,H,L,E), L given
__global__ __launch_bounds__(256) void gemm_kernel(const float* __restrict__ A,
    const float* __restrict__ W, const float* __restrict__ bias,
    float* __restrict__ C, int M, int N, int K, int epi, int L){
  __shared__ float As[16][65];
  __shared__ float Bs[16][65];
  const int tid = threadIdx.x;
  const int bm = blockIdx.y * 64, bn = blockIdx.x * 64;
  const int lr = tid >> 2;           // 0..63
  const int lc = (tid & 3) << 2;     // 0,4,8,12
  float acc[4][4] = {{0.f}};
  const int tx = (tid & 15) << 2, ty = (tid >> 4) << 2;
  for (int k0 = 0; k0 < K; k0 += 16){
    float4 av = *(const float4*)(A + (size_t)(bm + lr)*K + k0 + lc);
    float4 wv = *(const float4*)(W + (size_t)(bn + lr)*K + k0 + lc);
    __syncthreads();
    As[lc+0][lr]=av.x; As[lc+1][lr]=av.y; As[lc+2][lr]=av.z; As[lc+3][lr]=av.w;
    Bs[lc+0][lr]=wv.x; Bs[lc+1][lr]=wv.y; Bs[lc+2][lr]=wv.z; Bs[lc+3][lr]=wv.w;
    __syncthreads();
    #pragma unroll
    for (int kk = 0; kk < 16; ++kk){
      float a0=As[kk][ty+0], a1=As[kk][ty+1], a2=As[kk][ty+2], a3=As[kk][ty+3];
      float b0=Bs[kk][tx+0], b1=Bs[kk][tx+1], b2=Bs[kk][tx+2], b3=Bs[kk][tx+3];
      acc[0][0]+=a0*b0; acc[0][1]+=a0*b1; acc[0][2]+=a0*b2; acc[0][3]+=a0*b3;
      acc[1][0]+=a1*b0; acc[1][1]+=a1*b1; acc[1][2]+=a1*b2; acc[1][3]+=a1*b3;
      acc[2][0]+=a2*b0; acc[2][1]+=a2*b1; acc[2][2]+=a2*b2; acc[2][3]+=a2*b3;
      acc[3][0]+=a3*b0; acc[3][1]+=a3*b1; acc[3][2]+=a3*b2; acc[3][3]+=a3*b3;
    }
  }
  #pragma unroll
  for (int i=0;i<4;i++){
    #pragma unroll
    for (int j=0;j<4;j++){
      int m = bm + ty + i, n = bn + tx + j;
      float v = acc[i][j] + bias[n];
      if (epi == 1) v = 0.5f*v*(1.0f+erff(v*0.70710678118654752f));
      if (epi == 2){
        int b = m / L, l = m - b*L;
        int h = n >> 6, e = n & 63;
        C[(((size_t)(b*HH + h))*L + l)*EE + e] = v;
      } else {
        C[(size_t)m*N + n] = v;
      }
    }
  }
}

// ---------------- residual add + LayerNorm (y may be null) ----------------
__global__ __launch_bounds__(128) void add_ln_kernel(const float* __restrict__ x,
    const float* __restrict__ y, const float* __restrict__ g,
    const float* __restrict__ bb, float* __restrict__ out){
  const int row = blockIdx.x, t = threadIdx.x;
  float4 v = *(const float4*)(x + (size_t)row*DD + t*4);
  if (y){
    float4 w = *(const float4*)(y + (size_t)row*DD + t*4);
    v.x+=w.x; v.y+=w.y; v.z+=w.z; v.w+=w.w;
  }
  __shared__ float red[128];
  red[t] = v.x+v.y+v.z+v.w; __syncthreads();
  for (int o=64;o>0;o>>=1){ if (t<o) red[t]+=red[t+o]; __syncthreads(); }
  float mean = red[0] * (1.0f/512.0f);
  __syncthreads();
  float dx=v.x-mean, dy=v.y-mean, dz=v.z-mean, dw=v.w-mean;
  red[t] = dx*dx+dy*dy+dz*dz+dw*dw; __syncthreads();
  for (int o=64;o>0;o>>=1){ if (t<o) red[t]+=red[t+o]; __syncthreads(); }
  float rs = rsqrtf(red[0]*(1.0f/512.0f) + 1e-5f);
  float4 gg  = *(const float4*)(g  + t*4);
  float4 bv  = *(const float4*)(bb + t*4);
  float4 o4;
  o4.x = dx*rs*gg.x + bv.x;
  o4.y = dy*rs*gg.y + bv.y;
  o4.z = dz*rs*gg.z + bv.z;
  o4.w = dw*rs*gg.w + bv.w;
  *(float4*)(out + (size_t)row*DD + t*4) = o4;
}

// ---------------- depthwise distil conv (zero pad) ----------------
__global__ void distil_kernel(const float* __restrict__ x, const float* __restrict__ w,
    const float* __restrict__ bias, float* __restrict__ out, int L){
  size_t gid = (size_t)blockIdx.x*blockDim.x + threadIdx.x;
  int d = gid & (DD-1);
  size_t bl = gid >> 9;
  int l = (int)(bl % L); int b = (int)(bl / L);
  float acc = bias[d];
  const float* wd = w + (size_t)d*3;
  if (l > 0)     acc += x[(((size_t)b*L + l-1)*DD) + d] * wd[0];
  acc +=           x[(((size_t)b*L + l  )*DD) + d] * wd[1];
  if (l < L-1)   acc += x[(((size_t)b*L + l+1)*DD) + d] * wd[2];
  out[gid] = acc;
}

// ---------------- sampled-score M = max_j(q.k_idx) - sum_j/Lk ----------------
__global__ __launch_bounds__(256) void sampleM_kernel(const float* __restrict__ q,
    const float* __restrict__ k, const int* __restrict__ idx,
    float* __restrict__ M, int Lq, int Lk, int total){
  int gid = blockIdx.x*blockDim.x + threadIdx.x;
  if (gid >= total) return;
  int l = gid % Lq; int bh = gid / Lq;
  const float4* q4 = (const float4*)(q + (((size_t)bh*Lq) + l)*EE);
  float4 qr[16];
  #pragma unroll
  for (int e=0;e<16;e++) qr[e]=q4[e];
  float mx = -3.0e38f, sm = 0.f;
  for (int j=0;j<UU;j++){
    int ki = idx[l*UU + j];
    const float4* k4 = (const float4*)(k + (((size_t)bh*Lk) + ki)*EE);
    float d = 0.f;
    #pragma unroll
    for (int e=0;e<16;e++){
      float4 kv = k4[e];
      d += qr[e].x*kv.x + qr[e].y*kv.y + qr[e].z*kv.z + qr[e].w*kv.w;
    }
    mx = fmaxf(mx, d); sm += d;
  }
  M[gid] = mx - sm/(float)Lk;
}

// ---------------- stable top-k (u=35) per (b,h); destroys M ----------------
__global__ __launch_bounds__(256) void topk_kernel(float* __restrict__ M,
    int* __restrict__ mtop, int Lq){
  int bh = blockIdx.x, t = threadIdx.x;
  float* m = M + (size_t)bh*Lq;
  __shared__ float bv[256]; __shared__ int bi[256];
  for (int pass=0; pass<UU; ++pass){
    float best = -3.0e38f; int besti = 0x7fffffff;
    for (int i=t; i<Lq; i+=256){
      float v = m[i];
      if (v > best || (v == best && i < besti)){ best=v; besti=i; }
    }
    bv[t]=best; bi[t]=besti; __syncthreads();
    for (int s=128;s>0;s>>=1){
      if (t<s){
        if (bv[t+s] > bv[t] || (bv[t+s]==bv[t] && bi[t+s]<bi[t])){ bv[t]=bv[t+s]; bi[t]=bi[t+s]; }
      }
      __syncthreads();
    }
    if (t==0){ mtop[bh*UU + pass] = bi[0]; m[bi[0]] = -3.4e38f; }
    __syncthreads();
  }
}

// ---------------- V mean over keys ----------------
__global__ void vmean_kernel(const float* __restrict__ v, float* __restrict__ vm, int Lk){
  int bh = blockIdx.x, e = threadIdx.x; // 64 threads
  float s = 0.f;
  const float* base = v + (size_t)bh*Lk*EE + e;
  for (int l=0;l<Lk;l++) s += base[(size_t)l*EE];
  vm[bh*EE + e] = s / (float)Lk;
}

// ---------------- broadcast mean(V) into ctx (B,Lq,H,E) ----------------
__global__ __launch_bounds__(512) void fill_ctx_kernel(const float* __restrict__ vm,
    float* __restrict__ ctx, int Lq){
  int bl = blockIdx.x; int b = bl / Lq;
  int c = threadIdx.x;
  ctx[(size_t)bl*DD + c] = vm[(b*HH + (c>>6))*EE + (c & 63)];
}

// ---------------- full attention row for selected queries ----------------
__global__ __launch_bounds__(256) void attn_row_kernel(const float* __restrict__ q,
    const float* __restrict__ k, const float* __restrict__ v,
    const int* __restrict__ mtop, float* __restrict__ ctx, int Lq, int Lk){
  int ui = blockIdx.x % UU; int bh = blockIdx.x / UU;
  int h = bh % HH; int b = bh / HH;
  int row = mtop[bh*UU + ui];
  __shared__ float qrow[EE];
  __shared__ float p[1024];
  __shared__ float red[256];
  __shared__ float upd[4*EE];
  int t = threadIdx.x;
  if (t < EE) qrow[t] = q[(((size_t)bh*Lq) + row)*EE + t];
  __syncthreads();
  float lmax = -3.0e38f;
  for (int kk = t; kk < Lk; kk += 256){
    const float4* k4 = (const float4*)(k + (((size_t)bh*Lk) + kk)*EE);
    const float4* q4 = (const float4*)qrow;
    float d = 0.f;
    #pragma unroll
    for (int e=0;e<16;e++){
      float4 kv = k4[e]; float4 qv = q4[e];
      d += qv.x*kv.x + qv.y*kv.y + qv.z*kv.z + qv.w*kv.w;
    }
    d *= 0.125f; // 1/sqrt(64)
    p[kk] = d;
    lmax = fmaxf(lmax, d);
  }
  red[t] = lmax; __syncthreads();
  for (int s=128;s>0;s>>=1){ if (t<s) red[t]=fmaxf(red[t],red[t+s]); __syncthreads(); }
  float mx = red[0]; __syncthreads();
  float lsum = 0.f;
  for (int kk = t; kk < Lk; kk += 256){
    float e_ = expf(p[kk]-mx); p[kk]=e_; lsum += e_;
  }
  red[t] = lsum; __syncthreads();
  for (int s=128;s>0;s>>=1){ if (t<s) red[t]+=red[t+s]; __syncthreads(); }
  float inv = 1.0f/red[0];
  __syncthreads();
  int e = t & 63, g = t >> 6;
  float partial = 0.f;
  for (int kk = g; kk < Lk; kk += 4)
    partial += p[kk] * v[(((size_t)bh*Lk) + kk)*EE + e];
  upd[g*EE + e] = partial; __syncthreads();
  if (t < EE){
    float s2 = (upd[t] + upd[EE+t] + upd[2*EE+t] + upd[3*EE+t]) * inv;
    ctx[(((size_t)b*Lq + row)*HH + h)*EE + t] = s2;
  }
}

// ---------------- decoder self-attn "mix" permute ----------------
// ctx (B,L,H,E) -> view as (B,H,L,E) -> reshape (B, L, D) flat
__global__ void mix_kernel(const float* __restrict__ ctx, float* __restrict__ out){
  size_t gid = (size_t)blockIdx.x*blockDim.x + threadIdx.x; // B*512*512
  int b = (int)(gid >> 18);          // /(512*512)
  int f = (int)(gid & 262143);
  int hh = f >> 15;                  // /(512*64)
  int rem = f & 32767;
  int l = rem >> 6, e = rem & 63;
  out[gid] = ctx[(((size_t)b*LDQ + l)*HH + hh)*EE + e];
}

// ---------------- final projection, last PRED_LEN rows ----------------
__global__ __launch_bounds__(256) void proj_kernel(const float* __restrict__ dec,
    const float* __restrict__ pW, const float* __restrict__ pb, float* __restrict__ out){
  int r = blockIdx.x*4 + (threadIdx.x >> 6);   // 2048 outputs
  int lane = threadIdx.x & 63;
  int b = r >> 8, pp = r & 255;
  const float* drow = dec + (((size_t)b*LDQ) + 256 + pp)*DD;
  float s = 0.f;
  for (int e2 = lane; e2 < DD; e2 += 64) s += drow[e2]*pW[e2];
  for (int o=32;o>0;o>>=1) s += __shfl_down(s, o);
  if (lane == 0) out[r] = s + pb[0];
}

// ---------------- host orchestration ----------------
extern "C" void kernel_launch(void* const* d_in, const int* in_sizes, int n_in,
                              void* d_out, int out_size, void* d_ws, size_t ws_size,
                              hipStream_t stream){
  const float* x_enc     = (const float*)d_in[0];
  const float* x_dec     = (const float*)d_in[1];
  const float* enc_emb_W = (const float*)d_in[2];
  const float* enc_emb_b = (const float*)d_in[3];
  const float* dec_emb_W = (const float*)d_in[4];
  const float* dec_emb_b = (const float*)d_in[5];
  const float* enc_attn_W= (const float*)d_in[6];
  const float* enc_attn_b= (const float*)d_in[7];
  const float* enc_ff_W1 = (const float*)d_in[8];
  const float* enc_ff_b1 = (const float*)d_in[9];
  const float* enc_ff_W2 = (const float*)d_in[10];
  const float* enc_ff_b2 = (const float*)d_in[11];
  const float* enc_ln_g  = (const float*)d_in[12];
  const float* enc_ln_b  = (const float*)d_in[13];
  const float* distil_W  = (const float*)d_in[14];
  const float* distil_b  = (const float*)d_in[15];
  const float* enc_norm_g= (const float*)d_in[16];
  const float* enc_norm_b= (const float*)d_in[17];
  const float* dec_self_W= (const float*)d_in[18];
  const float* dec_self_b= (const float*)d_in[19];
  const float* dec_cross_W=(const float*)d_in[20];
  const float* dec_cross_b=(const float*)d_in[21];
  const float* dec_ff_W1 = (const float*)d_in[22];
  const float* dec_ff_b1 = (const float*)d_in[23];
  const float* dec_ff_W2 = (const float*)d_in[24];
  const float* dec_ff_b2 = (const float*)d_in[25];
  const float* dec_ln_g  = (const float*)d_in[26];
  const float* dec_ln_b  = (const float*)d_in[27];
  const float* dec_norm_g= (const float*)d_in[28];
  const float* dec_norm_b= (const float*)d_in[29];
  const float* proj_W    = (const float*)d_in[30];
  const float* proj_b    = (const float*)d_in[31];
  float* out = (float*)d_out;

  // workspace regions (floats): 6 x 16MB + small
  const size_t RSZ = (size_t)4 << 20; // 4M floats
  float* ws = (float*)d_ws;
  float* R0 = ws;            // enc state / dec state
  float* R1 = ws + 1*RSZ;    // enc final (kept for cross-attn)
  float* R2 = ws + 2*RSZ;    // q / x-temp
  float* R3 = ws + 3*RSZ;    // k / proj-out temp
  float* R4 = ws + 4*RSZ;    // v / ffn-hidden temp
  float* R5 = ws + 5*RSZ;    // ctx / ffn-out temp
  float* Mbuf  = ws + 6*RSZ;             // 65536 floats max
  float* vmean = Mbuf + BB*HH*1024;      // 4096 floats
  int*   idxb  = (int*)(vmean + BB*HH*EE);
  int*   mtop  = idxb + 1024*UU;
  size_t needed = ((size_t)(6*RSZ) + BB*HH*1024 + BB*HH*EE)*4 + (1024*UU + BB*HH*UU)*4;
  if (ws_size < needed){
    fprintf(stderr, "kernel_launch: ws too small (%zu < %zu)\n", ws_size, needed);
    return;
  }

  auto gemm = [&](const float* A, const float* W, const float* bias, float* C,
                  int M, int N, int K, int epi, int L){
    dim3 g(N/64, M/64);
    gemm_kernel<<<g, 256, 0, stream>>>(A, W, bias, C, M, N, K, epi, L);
  };

  // full ProbSparse attention core: q from qin (len Lq), k/v from kvin (len Lk),
  // result ctx (B,Lq,H,E) in R5. Uses R2,R3,R4 internally.
  auto attention = [&](const float* qin, int Lq, const float* kvin, int Lk,
                       const float* Wm, const float* bm, unsigned foldc){
    gemm(qin,  Wm + 0*DD*DD, bm + 0*DD, R2, BB*Lq, DD, DD, 2, Lq);
    gemm(kvin, Wm + 1*DD*DD, bm + 1*DD, R3, BB*Lk, DD, DD, 2, Lk);
    gemm(kvin, Wm + 2*DD*DD, bm + 2*DD, R4, BB*Lk, DD, DD, 2, Lk);
    // derive second split key of fold_in(key(1234), foldc), partitionable mode
    unsigned fk0, fk1, k2a, k2b;
    tf2x32(0u, 1234u, 0u, foldc, fk0, fk1);
    tf2x32(fk0, fk1, 0u, 1u, k2a, k2b);
    int n = Lq * UU;
    idx_kernel<<<(n+255)/256, 256, 0, stream>>>(k2a, k2b, idxb, n, Lk-1);
    int tot = BB*HH*Lq;
    sampleM_kernel<<<tot/256, 256, 0, stream>>>(R2, R3, idxb, Mbuf, Lq, Lk, tot);
    topk_kernel<<<BB*HH, 256, 0, stream>>>(Mbuf, mtop, Lq);
    vmean_kernel<<<BB*HH, 64, 0, stream>>>(R4, vmean, Lk);
    fill_ctx_kernel<<<BB*Lq, 512, 0, stream>>>(vmean, R5, Lq);
    attn_row_kernel<<<BB*HH*UU, 256, 0, stream>>>(R2, R3, R4, mtop, R5, Lq, Lk);
  };

  // ================= encoder =================
  embed_kernel<<<BB*LSQ, 512, 0, stream>>>(x_enc, enc_emb_W, enc_emb_b, R0, LSQ);
  for (int i=0;i<3;i++){
    const float* Wl = enc_attn_W + (size_t)i*4*DD*DD;
    const float* bl = enc_attn_b + (size_t)i*4*DD;
    attention(R0, LSQ, R0, LSQ, Wl, bl, (unsigned)i);
    gemm(R5, Wl + 3*DD*DD, bl + 3*DD, R3, BB*LSQ, DD, DD, 0, 0);                 // attn out-proj
    add_ln_kernel<<<BB*LSQ, 128, 0, stream>>>(R0, R3,
        enc_ln_g + (size_t)(i*2+0)*DD, enc_ln_b + (size_t)(i*2+0)*DD, R2);       // x
    gemm(R2, enc_ff_W1 + (size_t)i*DD*DD, enc_ff_b1 + (size_t)i*DD, R4, BB*LSQ, DD, DD, 1, 0);
    gemm(R4, enc_ff_W2 + (size_t)i*DD*DD, enc_ff_b2 + (size_t)i*DD, R5, BB*LSQ, DD, DD, 0, 0);
    add_ln_kernel<<<BB*LSQ, 128, 0, stream>>>(R2, R5,
        enc_ln_g + (size_t)(i*2+1)*DD, enc_ln_b + (size_t)(i*2+1)*DD, R0);       // enc
    if (i < 2){
      distil_kernel<<<(BB*LSQ*DD)/256, 256, 0, stream>>>(R0,
          distil_W + (size_t)i*DD*3, distil_b + (size_t)i*DD, R5, LSQ);
      hipMemcpyAsync(R0, R5, (size_t)BB*LSQ*DD*sizeof(float), hipMemcpyDeviceToDevice, stream);
    }
  }
  add_ln_kernel<<<BB*LSQ, 128, 0, stream>>>(R0, nullptr, enc_norm_g, enc_norm_b, R1); // enc final

  // ================= decoder =================
  embed_kernel<<<BB*LDQ, 512, 0, stream>>>(x_dec, dec_emb_W, dec_emb_b, R0, LDQ);
  for (int i=0;i<2;i++){
    const float* Wsf = dec_self_W + (size_t)i*4*DD*DD;
    const float* bsf = dec_self_b + (size_t)i*4*DD;
    attention(R0, LDQ, R0, LDQ, Wsf, bsf, (unsigned)(100+2*i));
    mix_kernel<<<(BB*LDQ*DD)/256, 256, 0, stream>>>(R5, R2);
    gemm(R2, Wsf + 3*DD*DD, bsf + 3*DD, R3, BB*LDQ, DD, DD, 0, 0);
    add_ln_kernel<<<BB*LDQ, 128, 0, stream>>>(R0, R3,
        dec_ln_g + (size_t)(i*3+0)*DD, dec_ln_b + (size_t)(i*3+0)*DD, R0);       // dec
    const float* Wc = dec_cross_W + (size_t)i*4*DD*DD;
    const float* bc = dec_cross_b + (size_t)i*4*DD;
    attention(R0, LDQ, R1, LSQ, Wc, bc, (unsigned)(101+2*i));
    gemm(R5, Wc + 3*DD*DD, bc + 3*DD, R3, BB*LDQ, DD, DD, 0, 0);
    add_ln_kernel<<<BB*LDQ, 128, 0, stream>>>(R0, R3,
        dec_ln_g + (size_t)(i*3+1)*DD, dec_ln_b + (size_t)(i*3+1)*DD, R2);       // x
    gemm(R2, dec_ff_W1 + (size_t)i*DD*DD, dec_ff_b1 + (size_t)i*DD, R4, BB*LDQ, DD, DD, 1, 0);
    gemm(R4, dec_ff_W2 + (size_t)i*DD*DD, dec_ff_b2 + (size_t)i*DD, R5, BB*LDQ, DD, DD, 0, 0);
    add_ln_kernel<<<BB*LDQ, 128, 0, stream>>>(R2, R5,
        dec_ln_g + (size_t)(i*3+2)*DD, dec_ln_b + (size_t)(i*3+2)*DD, R0);       // dec
  }
  add_ln_kernel<<<BB*LDQ, 128, 0, stream>>>(R0, nullptr, dec_norm_g, dec_norm_b, R2);
  proj_kernel<<<(BB*256)/4, 256, 0, stream>>>(R2, proj_W, proj_b, out);
}

// Round 6
// 5539.060 us; speedup vs baseline: 1.3155x; 1.3155x over previous
//
#include <hip/hip_runtime.h>
#include <cstdio>
#include <cstdint>

// ---------------- constants ----------------
#define BB 8
#define LSQ 1024
#define LDQ 512
#define DD 512
#define HH 8
#define EE 64
#define UU 35   // = 5*ceil(ln(1024)) = 5*ceil(ln(512)) = top-k u and sample count

typedef __attribute__((ext_vector_type(4))) float f32x4;
typedef __attribute__((ext_vector_type(8))) short bfrag; // 8 bf16 in 4 VGPRs
typedef __attribute__((ext_vector_type(4))) unsigned short us4;

__device__ inline unsigned short f2bf(float f){
  union { float f; unsigned u; } v; v.f = f;
  unsigned r = v.u + 0x7fffu + ((v.u >> 16) & 1u);  // RNE
  return (unsigned short)(r >> 16);
}

// ---------------- threefry2x32 (JAX-compatible) ----------------
__host__ __device__ inline unsigned rotl32(unsigned x, int r){ return (x<<r)|(x>>(32-r)); }

__host__ __device__ inline void tf2x32(unsigned k0, unsigned k1, unsigned x0, unsigned x1,
                                       unsigned &o0, unsigned &o1){
  unsigned ks2 = k0 ^ k1 ^ 0x1BD11BDAu;
#define TF_RND(rr) { x0 += x1; x1 = rotl32(x1, rr); x1 ^= x0; }
  x0 += k0; x1 += k1;
  TF_RND(13) TF_RND(15) TF_RND(26) TF_RND(6)
  x0 += k1; x1 += ks2 + 1u;
  TF_RND(17) TF_RND(29) TF_RND(16) TF_RND(24)
  x0 += ks2; x1 += k0 + 2u;
  TF_RND(13) TF_RND(15) TF_RND(26) TF_RND(6)
  x0 += k0; x1 += k1 + 3u;
  TF_RND(17) TF_RND(29) TF_RND(16) TF_RND(24)
  x0 += k1; x1 += ks2 + 4u;
  TF_RND(13) TF_RND(15) TF_RND(26) TF_RND(6)
  x0 += ks2; x1 += k0 + 5u;
#undef TF_RND
  o0 = x0; o1 = x1;
}

__global__ void idx_kernel(unsigned k2a, unsigned k2b, int* __restrict__ idx, int n, int lkMask){
  int i = blockIdx.x*blockDim.x + threadIdx.x;
  if (i >= n) return;
  unsigned o0,o1; tf2x32(k2a, k2b, 0u, (unsigned)i, o0, o1);
  idx[i] = (int)((o0 ^ o1) & (unsigned)lkMask);
}

// ---------------- token conv (wrap pad) + positional embedding ----------------
__global__ __launch_bounds__(512) void embed_kernel(const float* __restrict__ x,
    const float* __restrict__ W, const float* __restrict__ bias,
    float* __restrict__ out, int L){
  int bl = blockIdx.x; int b = bl / L; int l = bl - b*L;
  int d = threadIdx.x;
  __shared__ float xs[3][16];
  if (d < 48){
    int t = d / 16, c = d - t*16;
    int ll = l + t - 1; ll = (ll + L) % L;
    xs[t][c] = x[((size_t)b*L + ll)*16 + c];
  }
  __syncthreads();
  float acc = bias[d];
  const float* w = W + (size_t)d*48;   // W[d][c][t]
  #pragma unroll
  for (int c=0;c<16;c++){
    acc += xs[0][c]*w[c*3+0] + xs[1][c]*w[c*3+1] + xs[2][c]*w[c*3+2];
  }
  int p2 = (d >> 1) * 2;
  float freq = expf((float)p2 * (-(logf(10000.0f)/512.0f)));
  float ang = (float)l * freq;
  acc += (d & 1) ? cosf(ang) : sinf(ang);
  out[((size_t)b*L + l)*DD + d] = acc;
}

// ---------------- MFMA bf16 GEMM: C = A(MxK) * W(NxK)^T + bias ----------------
// 128x128 tile, BK=32, 4 waves each 64x64 (4x4 frags of 16x16x32).
// Each thread stages 4 row-groups (rows srow+32*rg) -> full 128x32 slab.
// fp32 global -> bf16 reg -> swizzled LDS (16B chunk ^= row&3).
// epi: 0 = plain, 1 = exact GELU, 2 = head-split write (B,H,L,E)
__global__ __launch_bounds__(256) void mfma_gemm(const float* __restrict__ A,
    const float* __restrict__ W, const float* __restrict__ bias,
    float* __restrict__ C, int M, int N, int K, int epi, int L){
  __shared__ unsigned short As[128*32];
  __shared__ unsigned short Bs[128*32];
  const int tid = threadIdx.x;
  const int bm = blockIdx.y * 128, bn = blockIdx.x * 128;
  const int wave = tid >> 6, lane = tid & 63;
  const int wm = (wave >> 1) * 64, wn = (wave & 1) * 64;
  f32x4 acc[4][4];
  #pragma unroll
  for (int i=0;i<4;i++)
    #pragma unroll
    for (int j=0;j<4;j++) acc[i][j] = 0.f;

  // staging coords: row = srow + 32*rg (rg=0..3), floats [scol, scol+4)
  const int srow = tid >> 3;           // 0..31
  const int scol = (tid & 7) * 4;      // 0,4,...,28
  const int cw  = scol * 2;                                   // byte col 0..56 step 8
  const int cwz = (cw & 8) | ((cw & 48) ^ ((srow & 3) << 4)); // swizzled (row&3 invariant under +32)
  // frag read offsets
  const int frow = lane & 15, fk = (lane >> 4) << 4;          // chunk byte 0..48

  for (int k0 = 0; k0 < K; k0 += 32){
    f32x4 av[4], wv[4];
    #pragma unroll
    for (int rg=0;rg<4;rg++){
      av[rg] = *(const f32x4*)(A + (size_t)(bm + srow + rg*32)*K + k0 + scol);
      wv[rg] = *(const f32x4*)(W + (size_t)(bn + srow + rg*32)*K + k0 + scol);
    }
    __syncthreads();   // prior iteration's frag reads done
    #pragma unroll
    for (int rg=0;rg<4;rg++){
      us4 a4; a4.x=f2bf(av[rg].x); a4.y=f2bf(av[rg].y); a4.z=f2bf(av[rg].z); a4.w=f2bf(av[rg].w);
      us4 b4; b4.x=f2bf(wv[rg].x); b4.y=f2bf(wv[rg].y); b4.z=f2bf(wv[rg].z); b4.w=f2bf(wv[rg].w);
      *(us4*)&As[(srow + rg*32)*32 + (cwz >> 1)] = a4;
      *(us4*)&Bs[(srow + rg*32)*32 + (cwz >> 1)] = b4;
    }
    __syncthreads();
    bfrag af[4], bf[4];
    #pragma unroll
    for (int i=0;i<4;i++){
      int r = wm + i*16 + frow;
      af[i] = *(const bfrag*)&As[r*32 + ((fk ^ ((r & 3) << 4)) >> 1)];
    }
    #pragma unroll
    for (int j=0;j<4;j++){
      int r = wn + j*16 + frow;
      bf[j] = *(const bfrag*)&Bs[r*32 + ((fk ^ ((r & 3) << 4)) >> 1)];
    }
    #pragma unroll
    for (int i=0;i<4;i++)
      #pragma unroll
      for (int j=0;j<4;j++)
        acc[i][j] = __builtin_amdgcn_mfma_f32_16x16x32_bf16(af[i], bf[j], acc[i][j], 0, 0, 0);
  }

  // epilogue: D row m = (lane>>4)*4+q, col n = lane&15  [m89 verified layout]
  #pragma unroll
  for (int j=0;j<4;j++){
    int n = bn + wn + j*16 + (lane & 15);
    float bs = bias[n];
    #pragma unroll
    for (int i=0;i<4;i++){
      #pragma unroll
      for (int q=0;q<4;q++){
        int m = bm + wm + i*16 + (lane >> 4)*4 + q;
        float v = acc[i][j][q] + bs;
        if (epi == 1) v = 0.5f*v*(1.0f+erff(v*0.70710678118654752f));
        if (epi == 2){
          int b = m / L, l = m - b*L;
          int h = n >> 6, e = n & 63;
          C[(((size_t)(b*HH + h))*L + l)*EE + e] = v;
        } else {
          C[(size_t)m*N + n] = v;
        }
      }
    }
  }
}

// ---------------- residual add + LayerNorm (y may be null) ----------------
__global__ __launch_bounds__(128) void add_ln_kernel(const float* __restrict__ x,
    const float* __restrict__ y, const float* __restrict__ g,
    const float* __restrict__ bb, float* __restrict__ out){
  const int row = blockIdx.x, t = threadIdx.x;
  float4 v = *(const float4*)(x + (size_t)row*DD + t*4);
  if (y){
    float4 w = *(const float4*)(y + (size_t)row*DD + t*4);
    v.x+=w.x; v.y+=w.y; v.z+=w.z; v.w+=w.w;
  }
  __shared__ float red[128];
  red[t] = v.x+v.y+v.z+v.w; __syncthreads();
  for (int o=64;o>0;o>>=1){ if (t<o) red[t]+=red[t+o]; __syncthreads(); }
  float mean = red[0] * (1.0f/512.0f);
  __syncthreads();
  float dx=v.x-mean, dy=v.y-mean, dz=v.z-mean, dw=v.w-mean;
  red[t] = dx*dx+dy*dy+dz*dz+dw*dw; __syncthreads();
  for (int o=64;o>0;o>>=1){ if (t<o) red[t]+=red[t+o]; __syncthreads(); }
  float rs = rsqrtf(red[0]*(1.0f/512.0f) + 1e-5f);
  float4 gg  = *(const float4*)(g  + t*4);
  float4 bv  = *(const float4*)(bb + t*4);
  float4 o4;
  o4.x = dx*rs*gg.x + bv.x;
  o4.y = dy*rs*gg.y + bv.y;
  o4.z = dz*rs*gg.z + bv.z;
  o4.w = dw*rs*gg.w + bv.w;
  *(float4*)(out + (size_t)row*DD + t*4) = o4;
}

// ---------------- depthwise distil conv (zero pad) ----------------
__global__ void distil_kernel(const float* __restrict__ x, const float* __restrict__ w,
    const float* __restrict__ bias, float* __restrict__ out, int L){
  size_t gid = (size_t)blockIdx.x*blockDim.x + threadIdx.x;
  int d = gid & (DD-1);
  size_t bl = gid >> 9;
  int l = (int)(bl % L); int b = (int)(bl / L);
  float acc = bias[d];
  const float* wd = w + (size_t)d*3;
  if (l > 0)     acc += x[(((size_t)b*L + l-1)*DD) + d] * wd[0];
  acc +=           x[(((size_t)b*L + l  )*DD) + d] * wd[1];
  if (l < L-1)   acc += x[(((size_t)b*L + l+1)*DD) + d] * wd[2];
  out[gid] = acc;
}

// ---------------- sampled-score M = max_j(q.k_idx) - sum_j/Lk ----------------
__global__ __launch_bounds__(256) void sampleM_kernel(const float* __restrict__ q,
    const float* __restrict__ k, const int* __restrict__ idx,
    float* __restrict__ M, int Lq, int Lk, int total){
  int gid = blockIdx.x*blockDim.x + threadIdx.x;
  if (gid >= total) return;
  int l = gid % Lq; int bh = gid / Lq;
  const float4* q4 = (const float4*)(q + (((size_t)bh*Lq) + l)*EE);
  float4 qr[16];
  #pragma unroll
  for (int e=0;e<16;e++) qr[e]=q4[e];
  float mx = -3.0e38f, sm = 0.f;
  for (int j=0;j<UU;j++){
    int ki = idx[l*UU + j];
    const float4* k4 = (const float4*)(k + (((size_t)bh*Lk) + ki)*EE);
    float d = 0.f;
    #pragma unroll
    for (int e=0;e<16;e++){
      float4 kv = k4[e];
      d += qr[e].x*kv.x + qr[e].y*kv.y + qr[e].z*kv.z + qr[e].w*kv.w;
    }
    mx = fmaxf(mx, d); sm += d;
  }
  M[gid] = mx - sm/(float)Lk;
}

// ---------------- stable top-k (u=35) per (b,h); destroys M ----------------
__global__ __launch_bounds__(256) void topk_kernel(float* __restrict__ M,
    int* __restrict__ mtop, int Lq){
  int bh = blockIdx.x, t = threadIdx.x;
  float* m = M + (size_t)bh*Lq;
  __shared__ float bv[256]; __shared__ int bi[256];
  for (int pass=0; pass<UU; ++pass){
    float best = -3.0e38f; int besti = 0x7fffffff;
    for (int i=t; i<Lq; i+=256){
      float v = m[i];
      if (v > best || (v == best && i < besti)){ best=v; besti=i; }
    }
    bv[t]=best; bi[t]=besti; __syncthreads();
    for (int s=128;s>0;s>>=1){
      if (t<s){
        if (bv[t+s] > bv[t] || (bv[t+s]==bv[t] && bi[t+s]<bi[t])){ bv[t]=bv[t+s]; bi[t]=bi[t+s]; }
      }
      __syncthreads();
    }
    if (t==0){
      int sel = bi[0];
      if ((unsigned)sel >= (unsigned)Lq) sel = 0;  // NaN-safety: never write OOB
      mtop[bh*UU + pass] = sel; m[sel] = -3.4e38f;
    }
    __syncthreads();
  }
}

// ---------------- V mean over keys ----------------
__global__ void vmean_kernel(const float* __restrict__ v, float* __restrict__ vm, int Lk){
  int bh = blockIdx.x, e = threadIdx.x; // 64 threads
  float s = 0.f;
  const float* base = v + (size_t)bh*Lk*EE + e;
  for (int l=0;l<Lk;l++) s += base[(size_t)l*EE];
  vm[bh*EE + e] = s / (float)Lk;
}

// ---------------- broadcast mean(V) into ctx (B,Lq,H,E) ----------------
__global__ __launch_bounds__(512) void fill_ctx_kernel(const float* __restrict__ vm,
    float* __restrict__ ctx, int Lq){
  int bl = blockIdx.x; int b = bl / Lq;
  int c = threadIdx.x;
  ctx[(size_t)bl*DD + c] = vm[(b*HH + (c>>6))*EE + (c & 63)];
}

// ---------------- fused multi-row attention: one block per (b,h) ----------------
// All 35 selected rows computed in ONE pass over K/V (LDS-staged, online softmax).
__global__ __launch_bounds__(256) void attn_fused(const float* __restrict__ q,
    const float* __restrict__ k, const float* __restrict__ v,
    const int* __restrict__ mtop, float* __restrict__ ctx, int Lq, int Lk){
  const int bh = blockIdx.x; const int h = bh & 7; const int b = bh >> 3;
  const int t = threadIdx.x; const int lane = t & 63; const int g = t >> 6;
  __shared__ float Qs[UU][EE];      // selected Q rows
  __shared__ float KT[EE][65];      // K chunk transposed, padded
  __shared__ float Vs[64][68];      // V chunk row-major, padded (16B-aligned rows)
  __shared__ float Ps[UU][64];      // probs for current chunk
  __shared__ int rows_s[UU];

  if (t < UU) rows_s[t] = mtop[bh*UU + t];
  __syncthreads();
  for (int r = g; r < UU; r += 4)
    Qs[r][lane] = q[((size_t)bh*Lq + rows_s[r])*EE + lane];

  float m_r[9], s_r[9], acc_r[9], rs_r[9];
  #pragma unroll
  for (int s=0;s<9;s++){ m_r[s] = -3.0e38f; s_r[s] = 0.f; acc_r[s] = 0.f; rs_r[s] = 0.f; }

  const int kr = t >> 2, c0 = (t & 3) * 16;  // staging coords

  for (int kc = 0; kc < Lk; kc += 64){
    __syncthreads();  // prev chunk's PV reads done
    const float* krow = k + ((size_t)bh*Lk + kc + kr)*EE + c0;
    const float* vrow = v + ((size_t)bh*Lk + kc + kr)*EE + c0;
    #pragma unroll
    for (int i2=0;i2<4;i2++){
      float4 kv = *(const float4*)(krow + i2*4);
      KT[c0+i2*4+0][kr] = kv.x; KT[c0+i2*4+1][kr] = kv.y;
      KT[c0+i2*4+2][kr] = kv.z; KT[c0+i2*4+3][kr] = kv.w;
      *(float4*)&Vs[kr][c0 + i2*4] = *(const float4*)(vrow + i2*4);
    }
    __syncthreads();
    #pragma unroll
    for (int s=0;s<9;s++){
      int r = g + 4*s; if (r >= UU) break;
      float sc = 0.f;
      #pragma unroll
      for (int d=0; d<EE; d++) sc += Qs[r][d] * KT[d][lane];
      sc *= 0.125f;
      float cm = sc;
      #pragma unroll
      for (int o=32;o>0;o>>=1) cm = fmaxf(cm, __shfl_xor(cm, o));
      float mnew = fmaxf(m_r[s], cm);
      float p = expf(sc - mnew);
      float scale = expf(m_r[s] - mnew);
      float ps = p;
      #pragma unroll
      for (int o=32;o>0;o>>=1) ps += __shfl_xor(ps, o);
      s_r[s] = s_r[s]*scale + ps;
      m_r[s] = mnew;
      rs_r[s] = scale;
      Ps[r][lane] = p;
    }
    __syncthreads();
    #pragma unroll
    for (int s=0;s<9;s++){
      int r = g + 4*s; if (r >= UU) break;
      float a = acc_r[s] * rs_r[s];
      #pragma unroll
      for (int c=0;c<64;c++) a += Ps[r][c] * Vs[c][lane];
      acc_r[s] = a;
    }
  }
  #pragma unroll
  for (int s=0;s<9;s++){
    int r = g + 4*s; if (r >= UU) break;
    int row = rows_s[r];
    ctx[(((size_t)b*Lq + row)*HH + h)*EE + lane] = acc_r[s] / s_r[s];
  }
}

// ---------------- decoder self-attn "mix" permute ----------------
__global__ void mix_kernel(const float* __restrict__ ctx, float* __restrict__ out){
  size_t gid = (size_t)blockIdx.x*blockDim.x + threadIdx.x; // B*512*512
  int b = (int)(gid >> 18);
  int f = (int)(gid & 262143);
  int hh = f >> 15;
  int rem = f & 32767;
  int l = rem >> 6, e = rem & 63;
  out[gid] = ctx[(((size_t)b*LDQ + l)*HH + hh)*EE + e];
}

// ---------------- final projection, last PRED_LEN rows ----------------
__global__ __launch_bounds__(256) void proj_kernel(const float* __restrict__ dec,
    const float* __restrict__ pW, const float* __restrict__ pb, float* __restrict__ out){
  int r = blockIdx.x*4 + (threadIdx.x >> 6);   // 2048 outputs
  int lane = threadIdx.x & 63;
  int b = r >> 8, pp = r & 255;
  const float* drow = dec + (((size_t)b*LDQ) + 256 + pp)*DD;
  float s = 0.f;
  for (int e2 = lane; e2 < DD; e2 += 64) s += drow[e2]*pW[e2];
  for (int o=32;o>0;o>>=1) s += __shfl_down(s, o);
  if (lane == 0) out[r] = s + pb[0];
}

// ---------------- host orchestration ----------------
extern "C" void kernel_launch(void* const* d_in, const int* in_sizes, int n_in,
                              void* d_out, int out_size, void* d_ws, size_t ws_size,
                              hipStream_t stream){
  const float* x_enc     = (const float*)d_in[0];
  const float* x_dec     = (const float*)d_in[1];
  const float* enc_emb_W = (const float*)d_in[2];
  const float* enc_emb_b = (const float*)d_in[3];
  const float* dec_emb_W = (const float*)d_in[4];
  const float* dec_emb_b = (const float*)d_in[5];
  const float* enc_attn_W= (const float*)d_in[6];
  const float* enc_attn_b= (const float*)d_in[7];
  const float* enc_ff_W1 = (const float*)d_in[8];
  const float* enc_ff_b1 = (const float*)d_in[9];
  const float* enc_ff_W2 = (const float*)d_in[10];
  const float* enc_ff_b2 = (const float*)d_in[11];
  const float* enc_ln_g  = (const float*)d_in[12];
  const float* enc_ln_b  = (const float*)d_in[13];
  const float* distil_W  = (const float*)d_in[14];
  const float* distil_b  = (const float*)d_in[15];
  const float* enc_norm_g= (const float*)d_in[16];
  const float* enc_norm_b= (const float*)d_in[17];
  const float* dec_self_W= (const float*)d_in[18];
  const float* dec_self_b= (const float*)d_in[19];
  const float* dec_cross_W=(const float*)d_in[20];
  const float* dec_cross_b=(const float*)d_in[21];
  const float* dec_ff_W1 = (const float*)d_in[22];
  const float* dec_ff_b1 = (const float*)d_in[23];
  const float* dec_ff_W2 = (const float*)d_in[24];
  const float* dec_ff_b2 = (const float*)d_in[25];
  const float* dec_ln_g  = (const float*)d_in[26];
  const float* dec_ln_b  = (const float*)d_in[27];
  const float* dec_norm_g= (const float*)d_in[28];
  const float* dec_norm_b= (const float*)d_in[29];
  const float* proj_W    = (const float*)d_in[30];
  const float* proj_b    = (const float*)d_in[31];
  float* out = (float*)d_out;

  const size_t RSZ = (size_t)4 << 20; // 4M floats
  float* ws = (float*)d_ws;
  float* R0 = ws;            // enc state / dec state
  float* R1 = ws + 1*RSZ;    // enc final (kept for cross-attn)
  float* R2 = ws + 2*RSZ;    // q / x-temp
  float* R3 = ws + 3*RSZ;    // k / proj-out temp
  float* R4 = ws + 4*RSZ;    // v / ffn-hidden temp
  float* R5 = ws + 5*RSZ;    // ctx / ffn-out temp
  float* Mbuf  = ws + 6*RSZ;
  float* vmean = Mbuf + BB*HH*1024;
  int*   idxb  = (int*)(vmean + BB*HH*EE);
  int*   mtop  = idxb + 1024*UU;
  size_t needed = ((size_t)(6*RSZ) + BB*HH*1024 + BB*HH*EE)*4 + (1024*UU + BB*HH*UU)*4;
  if (ws_size < needed){
    fprintf(stderr, "kernel_launch: ws too small (%zu < %zu)\n", ws_size, needed);
    return;
  }

  auto gemm = [&](const float* A, const float* W, const float* bias, float* C,
                  int M, int N, int K, int epi, int L){
    dim3 g(N/128, M/128);
    mfma_gemm<<<g, 256, 0, stream>>>(A, W, bias, C, M, N, K, epi, L);
  };

  auto attention = [&](const float* qin, int Lq, const float* kvin, int Lk,
                       const float* Wm, const float* bm, unsigned foldc){
    gemm(qin,  Wm + 0*DD*DD, bm + 0*DD, R2, BB*Lq, DD, DD, 2, Lq);
    gemm(kvin, Wm + 1*DD*DD, bm + 1*DD, R3, BB*Lk, DD, DD, 2, Lk);
    gemm(kvin, Wm + 2*DD*DD, bm + 2*DD, R4, BB*Lk, DD, DD, 2, Lk);
    unsigned fk0, fk1, k2a, k2b;
    tf2x32(0u, 1234u, 0u, foldc, fk0, fk1);
    tf2x32(fk0, fk1, 0u, 1u, k2a, k2b);
    int n = Lq * UU;
    idx_kernel<<<(n+255)/256, 256, 0, stream>>>(k2a, k2b, idxb, n, Lk-1);
    int tot = BB*HH*Lq;
    sampleM_kernel<<<tot/256, 256, 0, stream>>>(R2, R3, idxb, Mbuf, Lq, Lk, tot);
    topk_kernel<<<BB*HH, 256, 0, stream>>>(Mbuf, mtop, Lq);
    vmean_kernel<<<BB*HH, 64, 0, stream>>>(R4, vmean, Lk);
    fill_ctx_kernel<<<BB*Lq, 512, 0, stream>>>(vmean, R5, Lq);
    attn_fused<<<BB*HH, 256, 0, stream>>>(R2, R3, R4, mtop, R5, Lq, Lk);
  };

  // ================= encoder =================
  embed_kernel<<<BB*LSQ, 512, 0, stream>>>(x_enc, enc_emb_W, enc_emb_b, R0, LSQ);
  for (int i=0;i<3;i++){
    const float* Wl = enc_attn_W + (size_t)i*4*DD*DD;
    const float* bl = enc_attn_b + (size_t)i*4*DD;
    attention(R0, LSQ, R0, LSQ, Wl, bl, (unsigned)i);
    gemm(R5, Wl + 3*DD*DD, bl + 3*DD, R3, BB*LSQ, DD, DD, 0, 0);
    add_ln_kernel<<<BB*LSQ, 128, 0, stream>>>(R0, R3,
        enc_ln_g + (size_t)(i*2+0)*DD, enc_ln_b + (size_t)(i*2+0)*DD, R2);
    gemm(R2, enc_ff_W1 + (size_t)i*DD*DD, enc_ff_b1 + (size_t)i*DD, R4, BB*LSQ, DD, DD, 1, 0);
    gemm(R4, enc_ff_W2 + (size_t)i*DD*DD, enc_ff_b2 + (size_t)i*DD, R5, BB*LSQ, DD, DD, 0, 0);
    add_ln_kernel<<<BB*LSQ, 128, 0, stream>>>(R2, R5,
        enc_ln_g + (size_t)(i*2+1)*DD, enc_ln_b + (size_t)(i*2+1)*DD, R0);
    if (i < 2){
      distil_kernel<<<(BB*LSQ*DD)/256, 256, 0, stream>>>(R0,
          distil_W + (size_t)i*DD*3, distil_b + (size_t)i*DD, R5, LSQ);
      hipMemcpyAsync(R0, R5, (size_t)BB*LSQ*DD*sizeof(float), hipMemcpyDeviceToDevice, stream);
    }
  }
  add_ln_kernel<<<BB*LSQ, 128, 0, stream>>>(R0, nullptr, enc_norm_g, enc_norm_b, R1);

  // ================= decoder =================
  embed_kernel<<<BB*LDQ, 512, 0, stream>>>(x_dec, dec_emb_W, dec_emb_b, R0, LDQ);
  for (int i=0;i<2;i++){
    const float* Wsf = dec_self_W + (size_t)i*4*DD*DD;
    const float* bsf = dec_self_b + (size_t)i*4*DD;
    attention(R0, LDQ, R0, LDQ, Wsf, bsf, (unsigned)(100+2*i));
    mix_kernel<<<(BB*LDQ*DD)/256, 256, 0, stream>>>(R5, R2);
    gemm(R2, Wsf + 3*DD*DD, bsf + 3*DD, R3, BB*LDQ, DD, DD, 0, 0);
    add_ln_kernel<<<BB*LDQ, 128, 0, stream>>>(R0, R3,
        dec_ln_g + (size_t)(i*3+0)*DD, dec_ln_b + (size_t)(i*3+0)*DD, R0);
    const float* Wc = dec_cross_W + (size_t)i*4*DD*DD;
    const float* bc = dec_cross_b + (size_t)i*4*DD;
    attention(R0, LDQ, R1, LSQ, Wc, bc, (unsigned)(101+2*i));
    gemm(R5, Wc + 3*DD*DD, bc + 3*DD, R3, BB*LDQ, DD, DD, 0, 0);
    add_ln_kernel<<<BB*LDQ, 128, 0, stream>>>(R0, R3,
        dec_ln_g + (size_t)(i*3+1)*DD, dec_ln_b + (size_t)(i*3+1)*DD, R2);
    gemm(R2, dec_ff_W1 + (size_t)i*DD*DD, dec_ff_b1 + (size_t)i*DD, R4, BB*LDQ, DD, DD, 1, 0);
    gemm(R4, dec_ff_W2 + (size_t)i*DD*DD, dec_ff_b2 + (size_t)i*DD, R5, BB*LDQ, DD, DD, 0, 0);
    add_ln_kernel<<<BB*LDQ, 128, 0, stream>>>(R2, R5,
        dec_ln_g + (size_t)(i*3+2)*DD, dec_ln_b + (size_t)(i*3+2)*DD, R0);
  }
  add_ln_kernel<<<BB*LDQ, 128, 0, stream>>>(R0, nullptr, dec_norm_g, dec_norm_b, R2);
  proj_kernel<<<(BB*256)/4, 256, 0, stream>>>(R2, proj_W, proj_b, out);
}

// Round 11
// 2965.462 us; speedup vs baseline: 2.4572x; 1.8679x over previous
//
#include <hip/hip_runtime.h>
#include <cstdio>
#include <cstdint>

// ---------------- constants ----------------
#define BB 8
#define LSQ 1024
#define LDQ 512
#define DD 512
#define HH 8
#define EE 64
#define UU 35            // = 5*ceil(ln(1024)) = 5*ceil(ln(512))
#define RSZF ((size_t)(4u<<20))   // region stride in floats (16 MB)

typedef __attribute__((ext_vector_type(4))) float f32x4;
typedef __attribute__((ext_vector_type(8))) short bfrag; // 8 bf16 in 4 VGPRs
typedef __attribute__((ext_vector_type(4))) unsigned short us4;

__device__ inline unsigned short f2bf(float f){
  union { float f; unsigned u; } v; v.f = f;
  unsigned r = v.u + 0x7fffu + ((v.u >> 16) & 1u);  // RNE
  return (unsigned short)(r >> 16);
}

// ---------------- threefry2x32 (JAX-compatible) ----------------
__host__ __device__ inline unsigned rotl32(unsigned x, int r){ return (x<<r)|(x>>(32-r)); }

__host__ __device__ inline void tf2x32(unsigned k0, unsigned k1, unsigned x0, unsigned x1,
                                       unsigned &o0, unsigned &o1){
  unsigned ks2 = k0 ^ k1 ^ 0x1BD11BDAu;
#define TF_RND(rr) { x0 += x1; x1 = rotl32(x1, rr); x1 ^= x0; }
  x0 += k0; x1 += k1;
  TF_RND(13) TF_RND(15) TF_RND(26) TF_RND(6)
  x0 += k1; x1 += ks2 + 1u;
  TF_RND(17) TF_RND(29) TF_RND(16) TF_RND(24)
  x0 += ks2; x1 += k0 + 2u;
  TF_RND(13) TF_RND(15) TF_RND(26) TF_RND(6)
  x0 += k0; x1 += k1 + 3u;
  TF_RND(17) TF_RND(29) TF_RND(16) TF_RND(24)
  x0 += k1; x1 += ks2 + 4u;
  TF_RND(13) TF_RND(15) TF_RND(26) TF_RND(6)
  x0 += ks2; x1 += k0 + 5u;
#undef TF_RND
  o0 = x0; o1 = x1;
}

__global__ void idx_kernel(unsigned k2a, unsigned k2b, int* __restrict__ idx, int n, int lkMask){
  int i = blockIdx.x*blockDim.x + threadIdx.x;
  if (i >= n) return;
  unsigned o0,o1; tf2x32(k2a, k2b, 0u, (unsigned)i, o0, o1);
  idx[i] = (int)((o0 ^ o1) & (unsigned)lkMask);
}

// ---------------- token conv (wrap pad) + positional embedding ----------------
__global__ __launch_bounds__(512) void embed_kernel(const float* __restrict__ x,
    const float* __restrict__ W, const float* __restrict__ bias,
    float* __restrict__ out, int L){
  int bl = blockIdx.x; int b = bl / L; int l = bl - b*L;
  int d = threadIdx.x;
  __shared__ float xs[3][16];
  if (d < 48){
    int t = d / 16, c = d - t*16;
    int ll = l + t - 1; ll = (ll + L) % L;
    xs[t][c] = x[((size_t)b*L + ll)*16 + c];
  }
  __syncthreads();
  float acc = bias[d];
  const float* w = W + (size_t)d*48;   // W[d][c][t]
  #pragma unroll
  for (int c=0;c<16;c++){
    acc += xs[0][c]*w[c*3+0] + xs[1][c]*w[c*3+1] + xs[2][c]*w[c*3+2];
  }
  int p2 = (d >> 1) * 2;
  float freq = expf((float)p2 * (-(logf(10000.0f)/512.0f)));
  float ang = (float)l * freq;
  acc += (d & 1) ? cosf(ang) : sinf(ang);
  out[((size_t)b*L + l)*DD + d] = acc;
}

// ---------------- MFMA bf16 GEMM: C = A(MxK) * W(NxK)^T + bias ----------------
// 128x128 tile, BK=32, 4 waves each 64x64 (4x4 frags of 16x16x32).
// epi: 0 = plain, 1 = exact GELU, 2 = head-split write (B,H,L,E) with
//      region routing which = n>>9 (stride RSZF) -> supports fused QKV / KV.
__global__ __launch_bounds__(256) void mfma_gemm(const float* __restrict__ A,
    const float* __restrict__ W, const float* __restrict__ bias,
    float* __restrict__ C, int M, int N, int K, int epi, int L){
  __shared__ unsigned short As[128*32];
  __shared__ unsigned short Bs[128*32];
  const int tid = threadIdx.x;
  const int bm = blockIdx.y * 128, bn = blockIdx.x * 128;
  const int wave = tid >> 6, lane = tid & 63;
  const int wm = (wave >> 1) * 64, wn = (wave & 1) * 64;
  f32x4 acc[4][4];
  #pragma unroll
  for (int i=0;i<4;i++)
    #pragma unroll
    for (int j=0;j<4;j++) acc[i][j] = 0.f;

  const int srow = tid >> 3;           // 0..31
  const int scol = (tid & 7) * 4;      // 0,4,...,28
  const int cw  = scol * 2;
  const int cwz = (cw & 8) | ((cw & 48) ^ ((srow & 3) << 4)); // swizzle (row&3 invariant under +32)
  const int frow = lane & 15, fk = (lane >> 4) << 4;

  for (int k0 = 0; k0 < K; k0 += 32){
    f32x4 av[4], wv[4];
    #pragma unroll
    for (int rg=0;rg<4;rg++){
      av[rg] = *(const f32x4*)(A + (size_t)(bm + srow + rg*32)*K + k0 + scol);
      wv[rg] = *(const f32x4*)(W + (size_t)(bn + srow + rg*32)*K + k0 + scol);
    }
    __syncthreads();
    #pragma unroll
    for (int rg=0;rg<4;rg++){
      us4 a4; a4.x=f2bf(av[rg].x); a4.y=f2bf(av[rg].y); a4.z=f2bf(av[rg].z); a4.w=f2bf(av[rg].w);
      us4 b4; b4.x=f2bf(wv[rg].x); b4.y=f2bf(wv[rg].y); b4.z=f2bf(wv[rg].z); b4.w=f2bf(wv[rg].w);
      *(us4*)&As[(srow + rg*32)*32 + (cwz >> 1)] = a4;
      *(us4*)&Bs[(srow + rg*32)*32 + (cwz >> 1)] = b4;
    }
    __syncthreads();
    bfrag af[4], bf[4];
    #pragma unroll
    for (int i=0;i<4;i++){
      int r = wm + i*16 + frow;
      af[i] = *(const bfrag*)&As[r*32 + ((fk ^ ((r & 3) << 4)) >> 1)];
    }
    #pragma unroll
    for (int j=0;j<4;j++){
      int r = wn + j*16 + frow;
      bf[j] = *(const bfrag*)&Bs[r*32 + ((fk ^ ((r & 3) << 4)) >> 1)];
    }
    #pragma unroll
    for (int i=0;i<4;i++)
      #pragma unroll
      for (int j=0;j<4;j++)
        acc[i][j] = __builtin_amdgcn_mfma_f32_16x16x32_bf16(af[i], bf[j], acc[i][j], 0, 0, 0);
  }

  #pragma unroll
  for (int j=0;j<4;j++){
    int n = bn + wn + j*16 + (lane & 15);
    float bs = bias[n];
    #pragma unroll
    for (int i=0;i<4;i++){
      #pragma unroll
      for (int q=0;q<4;q++){
        int m = bm + wm + i*16 + (lane >> 4)*4 + q;
        float v = acc[i][j][q] + bs;
        if (epi == 1) v = 0.5f*v*(1.0f+erff(v*0.70710678118654752f));
        if (epi == 2){
          int b = m / L, l = m - b*L;
          int which = n >> 9;               // region (q/k/v)
          int h = (n >> 6) & 7, e = n & 63;
          C[(size_t)which*RSZF + (((size_t)(b*HH + h))*L + l)*EE + e] = v;
        } else {
          C[(size_t)m*N + n] = v;
        }
      }
    }
  }
}

// ---------------- residual add + LayerNorm (y may be null) ----------------
__global__ __launch_bounds__(128) void add_ln_kernel(const float* __restrict__ x,
    const float* __restrict__ y, const float* __restrict__ g,
    const float* __restrict__ bb, float* __restrict__ out){
  const int row = blockIdx.x, t = threadIdx.x;
  float4 v = *(const float4*)(x + (size_t)row*DD + t*4);
  if (y){
    float4 w = *(const float4*)(y + (size_t)row*DD + t*4);
    v.x+=w.x; v.y+=w.y; v.z+=w.z; v.w+=w.w;
  }
  __shared__ float red[128];
  red[t] = v.x+v.y+v.z+v.w; __syncthreads();
  for (int o=64;o>0;o>>=1){ if (t<o) red[t]+=red[t+o]; __syncthreads(); }
  float mean = red[0] * (1.0f/512.0f);
  __syncthreads();
  float dx=v.x-mean, dy=v.y-mean, dz=v.z-mean, dw=v.w-mean;
  red[t] = dx*dx+dy*dy+dz*dz+dw*dw; __syncthreads();
  for (int o=64;o>0;o>>=1){ if (t<o) red[t]+=red[t+o]; __syncthreads(); }
  float rs = rsqrtf(red[0]*(1.0f/512.0f) + 1e-5f);
  float4 gg  = *(const float4*)(g  + t*4);
  float4 bv  = *(const float4*)(bb + t*4);
  float4 o4;
  o4.x = dx*rs*gg.x + bv.x;
  o4.y = dy*rs*gg.y + bv.y;
  o4.z = dz*rs*gg.z + bv.z;
  o4.w = dw*rs*gg.w + bv.w;
  *(float4*)(out + (size_t)row*DD + t*4) = o4;
}

// ---------------- depthwise distil conv (zero pad) ----------------
__global__ void distil_kernel(const float* __restrict__ x, const float* __restrict__ w,
    const float* __restrict__ bias, float* __restrict__ out, int L){
  size_t gid = (size_t)blockIdx.x*blockDim.x + threadIdx.x;
  int d = gid & (DD-1);
  size_t bl = gid >> 9;
  int l = (int)(bl % L); int b = (int)(bl / L);
  float acc = bias[d];
  const float* wd = w + (size_t)d*3;
  if (l > 0)     acc += x[(((size_t)b*L + l-1)*DD) + d] * wd[0];
  acc +=           x[(((size_t)b*L + l  )*DD) + d] * wd[1];
  if (l < L-1)   acc += x[(((size_t)b*L + l+1)*DD) + d] * wd[2];
  out[gid] = acc;
}

// ---------------- sampled-score, wave per query: coalesced K rows ----------------
__global__ __launch_bounds__(256) void sampleM_wave(const float* __restrict__ q,
    const float* __restrict__ k, const int* __restrict__ idx,
    float* __restrict__ M, int lqShift, int Lk){
  int wid = (int)((blockIdx.x*(size_t)blockDim.x + threadIdx.x) >> 6);
  int lane = threadIdx.x & 63;
  int l  = wid & ((1 << lqShift) - 1);
  int bh = wid >> lqShift;
  float qe = q[(((size_t)bh << lqShift) + l)*EE + lane];
  int myidx = (lane < UU) ? idx[l*UU + lane] : 0;
  float mx = -3.0e38f, sm = 0.f;
  for (int j=0;j<UU;j++){
    int ki = __shfl(myidx, j);
    float p = qe * k[((size_t)bh*Lk + ki)*EE + lane];
    #pragma unroll
    for (int o=32;o>0;o>>=1) p += __shfl_xor(p, o);
    mx = fmaxf(mx, p); sm += p;
  }
  if (lane == 0) M[wid] = mx - sm/(float)Lk;
}

// ---------------- stable top-k (u=35), register-resident ----------------
__global__ __launch_bounds__(256) void topk_kernel(const float* __restrict__ M,
    int* __restrict__ mtop, int Lq){
  int bh = blockIdx.x, t = threadIdx.x;
  const float* m = M + (size_t)bh*Lq;
  const int nv = Lq >> 8;       // 4 (enc) or 2 (dec)
  float v[4]; int vi[4];
  for (int i=0;i<nv;i++){ vi[i] = t + (i<<8); v[i] = m[vi[i]]; }
  __shared__ float wv_s[4]; __shared__ int wi_s[4]; __shared__ int winner;
  for (int pass=0; pass<UU; ++pass){
    float best = v[0]; int bi = vi[0];
    for (int i=1;i<nv;i++) if (v[i] > best || (v[i] == best && vi[i] < bi)){ best=v[i]; bi=vi[i]; }
    #pragma unroll
    for (int o=32;o>0;o>>=1){
      float ov = __shfl_xor(best, o); int oi = __shfl_xor(bi, o);
      if (ov > best || (ov == best && oi < bi)){ best=ov; bi=oi; }
    }
    if ((t & 63) == 0){ wv_s[t>>6] = best; wi_s[t>>6] = bi; }
    __syncthreads();
    if (t == 0){
      float bb2 = wv_s[0]; int bbi = wi_s[0];
      for (int w2=1;w2<4;w2++)
        if (wv_s[w2] > bb2 || (wv_s[w2] == bb2 && wi_s[w2] < bbi)){ bb2=wv_s[w2]; bbi=wi_s[w2]; }
      if ((unsigned)bbi >= (unsigned)Lq) bbi = 0;   // NaN-safety
      mtop[bh*UU + pass] = bbi; winner = bbi;
    }
    __syncthreads();
    for (int i=0;i<nv;i++) if (vi[i] == winner) v[i] = -3.4e38f;
  }
}

// ---------------- V mean over keys (16-way row-parallel) ----------------
__global__ __launch_bounds__(1024) void vmean_kernel(const float* __restrict__ v,
    float* __restrict__ vm, int Lk){
  int bh = blockIdx.x; int t = threadIdx.x;
  int e = t & 63, g = t >> 6;   // 16 groups
  float s = 0.f;
  for (int r = g; r < Lk; r += 16) s += v[((size_t)bh*Lk + r)*EE + e];
  __shared__ float red[16][64];
  red[g][e] = s; __syncthreads();
  if (g < 8) red[g][e] += red[g+8][e];
  __syncthreads();
  if (g < 4) red[g][e] += red[g+4][e];
  __syncthreads();
  if (g < 2) red[g][e] += red[g+2][e];
  __syncthreads();
  if (g == 0) vm[bh*EE + e] = (red[0][e] + red[1][e]) / (float)Lk;
}

// ---------------- broadcast mean(V) into ctx (B,Lq,H,E) ----------------
__global__ __launch_bounds__(512) void fill_ctx_kernel(const float* __restrict__ vm,
    float* __restrict__ ctx, int Lq){
  int bl = blockIdx.x; int b = bl / Lq;
  int c = threadIdx.x;
  ctx[(size_t)bl*DD + c] = vm[(b*HH + (c>>6))*EE + (c & 63)];
}

// ---------------- split-K attention, phase 1: per-slice partials ----------------
// grid (nslice, BB*HH); each block handles 64 keys for all 35 rows.
// part[bh][slice][r][66] = { acc[64], m, s }
__global__ __launch_bounds__(256) void attn_part(const float* __restrict__ q,
    const float* __restrict__ k, const float* __restrict__ v,
    const int* __restrict__ mtop, float* __restrict__ part, int Lq, int Lk){
  const int slice = blockIdx.x, bh = blockIdx.y, nslice = gridDim.x;
  const int t = threadIdx.x, lane = t & 63, g = t >> 6;
  const int kc = slice * 64;
  __shared__ float Qs[UU][EE];
  __shared__ float KT[EE][65];
  __shared__ float Vs[64][68];
  __shared__ float Ps[UU][64];
  __shared__ int rows_s[UU];
  if (t < UU) rows_s[t] = mtop[bh*UU + t];
  __syncthreads();
  for (int r = g; r < UU; r += 4)
    Qs[r][lane] = q[((size_t)bh*Lq + rows_s[r])*EE + lane];
  const int kr = t >> 2, c0 = (t & 3) * 16;
  const float* krow = k + ((size_t)bh*Lk + kc + kr)*EE + c0;
  const float* vrow = v + ((size_t)bh*Lk + kc + kr)*EE + c0;
  #pragma unroll
  for (int i2=0;i2<4;i2++){
    float4 kv = *(const float4*)(krow + i2*4);
    KT[c0+i2*4+0][kr] = kv.x; KT[c0+i2*4+1][kr] = kv.y;
    KT[c0+i2*4+2][kr] = kv.z; KT[c0+i2*4+3][kr] = kv.w;
    *(float4*)&Vs[kr][c0 + i2*4] = *(const float4*)(vrow + i2*4);
  }
  __syncthreads();
  float* pb = part + (((size_t)bh*nslice + slice)*UU)*66;
  #pragma unroll
  for (int s=0;s<9;s++){
    int r = g + 4*s; if (r >= UU) break;
    float sc = 0.f;
    #pragma unroll
    for (int d=0; d<EE; d++) sc += Qs[r][d] * KT[d][lane];
    sc *= 0.125f;
    float cm = sc;
    #pragma unroll
    for (int o=32;o>0;o>>=1) cm = fmaxf(cm, __shfl_xor(cm, o));
    float p = expf(sc - cm);
    float ps = p;
    #pragma unroll
    for (int o=32;o>0;o>>=1) ps += __shfl_xor(ps, o);
    Ps[r][lane] = p;
    if (lane == 0){ pb[r*66 + 64] = cm; pb[r*66 + 65] = ps; }
  }
  __syncthreads();
  #pragma unroll
  for (int s=0;s<9;s++){
    int r = g + 4*s; if (r >= UU) break;
    float a = 0.f;
    #pragma unroll
    for (int c=0;c<64;c++) a += Ps[r][c] * Vs[c][lane];
    pb[r*66 + lane] = a;
  }
}

// ---------------- split-K attention, phase 2: merge slices ----------------
__global__ __launch_bounds__(64) void attn_reduce(const float* __restrict__ part,
    const int* __restrict__ mtop, float* __restrict__ ctx, int Lq, int nslice){
  int blk = blockIdx.x; int r = blk % UU; int bh = blk / UU;
  int h = bh & 7, b = bh >> 3;
  int lane = threadIdx.x;
  const float* pb = part + ((size_t)bh*nslice*UU + r)*66;
  float mg = -3.0e38f;
  for (int i=0;i<nslice;i++) mg = fmaxf(mg, pb[(size_t)i*UU*66 + 64]);
  float acc = 0.f, den = 0.f;
  for (int i=0;i<nslice;i++){
    float sc = expf(pb[(size_t)i*UU*66 + 64] - mg);
    acc += sc * pb[(size_t)i*UU*66 + lane];
    den += sc * pb[(size_t)i*UU*66 + 65];
  }
  int row = mtop[bh*UU + r];
  ctx[(((size_t)b*Lq + row)*HH + h)*EE + lane] = acc/den;
}

// ---------------- decoder self-attn "mix" permute ----------------
__global__ void mix_kernel(const float* __restrict__ ctx, float* __restrict__ out){
  size_t gid = (size_t)blockIdx.x*blockDim.x + threadIdx.x; // B*512*512
  int b = (int)(gid >> 18);
  int f = (int)(gid & 262143);
  int hh = f >> 15;
  int rem = f & 32767;
  int l = rem >> 6, e = rem & 63;
  out[gid] = ctx[(((size_t)b*LDQ + l)*HH + hh)*EE + e];
}

// ---------------- final projection, last PRED_LEN rows ----------------
__global__ __launch_bounds__(256) void proj_kernel(const float* __restrict__ dec,
    const float* __restrict__ pW, const float* __restrict__ pb, float* __restrict__ out){
  int r = blockIdx.x*4 + (threadIdx.x >> 6);   // 2048 outputs
  int lane = threadIdx.x & 63;
  int b = r >> 8, pp = r & 255;
  const float* drow = dec + (((size_t)b*LDQ) + 256 + pp)*DD;
  float s = 0.f;
  for (int e2 = lane; e2 < DD; e2 += 64) s += drow[e2]*pW[e2];
  for (int o=32;o>0;o>>=1) s += __shfl_down(s, o);
  if (lane == 0) out[r] = s + pb[0];
}

// ---------------- host orchestration ----------------
extern "C" void kernel_launch(void* const* d_in, const int* in_sizes, int n_in,
                              void* d_out, int out_size, void* d_ws, size_t ws_size,
                              hipStream_t stream){
  const float* x_enc     = (const float*)d_in[0];
  const float* x_dec     = (const float*)d_in[1];
  const float* enc_emb_W = (const float*)d_in[2];
  const float* enc_emb_b = (const float*)d_in[3];
  const float* dec_emb_W = (const float*)d_in[4];
  const float* dec_emb_b = (const float*)d_in[5];
  const float* enc_attn_W= (const float*)d_in[6];
  const float* enc_attn_b= (const float*)d_in[7];
  const float* enc_ff_W1 = (const float*)d_in[8];
  const float* enc_ff_b1 = (const float*)d_in[9];
  const float* enc_ff_W2 = (const float*)d_in[10];
  const float* enc_ff_b2 = (const float*)d_in[11];
  const float* enc_ln_g  = (const float*)d_in[12];
  const float* enc_ln_b  = (const float*)d_in[13];
  const float* distil_W  = (const float*)d_in[14];
  const float* distil_b  = (const float*)d_in[15];
  const float* enc_norm_g= (const float*)d_in[16];
  const float* enc_norm_b= (const float*)d_in[17];
  const float* dec_self_W= (const float*)d_in[18];
  const float* dec_self_b= (const float*)d_in[19];
  const float* dec_cross_W=(const float*)d_in[20];
  const float* dec_cross_b=(const float*)d_in[21];
  const float* dec_ff_W1 = (const float*)d_in[22];
  const float* dec_ff_b1 = (const float*)d_in[23];
  const float* dec_ff_W2 = (const float*)d_in[24];
  const float* dec_ff_b2 = (const float*)d_in[25];
  const float* dec_ln_g  = (const float*)d_in[26];
  const float* dec_ln_b  = (const float*)d_in[27];
  const float* dec_norm_g= (const float*)d_in[28];
  const float* dec_norm_b= (const float*)d_in[29];
  const float* proj_W    = (const float*)d_in[30];
  const float* proj_b    = (const float*)d_in[31];
  float* out = (float*)d_out;

  float* ws = (float*)d_ws;
  float* R0 = ws;            // enc state / dec state
  float* R1 = ws + 1*RSZF;   // enc final (kept for cross-attn)
  float* R2 = ws + 2*RSZF;   // q
  float* R3 = ws + 3*RSZF;   // k   (R2+RSZF — fused QKV routing relies on this)
  float* R4 = ws + 4*RSZF;   // v
  float* R5 = ws + 5*RSZF;   // ctx / ffn temps
  float* Mbuf  = ws + 6*RSZF;            // 65536
  float* vmean = Mbuf + BB*HH*1024;      // 4096
  float* part  = vmean + BB*HH*EE;       // 64*16*35*66 = 2,365,440 floats
  int*   idxb  = (int*)(part + (size_t)BB*HH*16*UU*66);
  int*   mtop  = idxb + 1024*UU;
  size_t needed = ((size_t)(6*RSZF) + BB*HH*1024 + BB*HH*EE + (size_t)BB*HH*16*UU*66)*4
                + (1024*UU + BB*HH*UU)*4;
  if (ws_size < needed){
    fprintf(stderr, "kernel_launch: ws too small (%zu < %zu)\n", ws_size, needed);
    return;
  }

  auto gemm = [&](const float* A, const float* W, const float* bias, float* C,
                  int M, int N, int K, int epi, int L){
    dim3 g(N/128, M/128);
    mfma_gemm<<<g, 256, 0, stream>>>(A, W, bias, C, M, N, K, epi, L);
  };

  auto attention = [&](const float* qin, int Lq, const float* kvin, int Lk,
                       const float* Wm, const float* bm, unsigned foldc, bool self){
    if (self){
      gemm(qin, Wm, bm, R2, BB*Lq, 3*DD, DD, 2, Lq);          // fused q,k,v -> R2,R3,R4
    } else {
      gemm(qin,  Wm + 0*DD*DD, bm + 0*DD, R2, BB*Lq, DD, DD, 2, Lq);
      gemm(kvin, Wm + 1*DD*DD, bm + 1*DD, R3, BB*Lk, 2*DD, DD, 2, Lk); // fused k,v -> R3,R4
    }
    unsigned fk0, fk1, k2a, k2b;
    tf2x32(0u, 1234u, 0u, foldc, fk0, fk1);
    tf2x32(fk0, fk1, 0u, 1u, k2a, k2b);
    int n = Lq * UU;
    idx_kernel<<<(n+255)/256, 256, 0, stream>>>(k2a, k2b, idxb, n, Lk-1);
    int lqShift = (Lq == 1024) ? 10 : 9;
    int nthreads = BB*HH*Lq*64;
    sampleM_wave<<<nthreads/256, 256, 0, stream>>>(R2, R3, idxb, Mbuf, lqShift, Lk);
    topk_kernel<<<BB*HH, 256, 0, stream>>>(Mbuf, mtop, Lq);
    vmean_kernel<<<BB*HH, 1024, 0, stream>>>(R4, vmean, Lk);
    fill_ctx_kernel<<<BB*Lq, 512, 0, stream>>>(vmean, R5, Lq);
    int nslice = Lk / 64;
    attn_part<<<dim3(nslice, BB*HH), 256, 0, stream>>>(R2, R3, R4, mtop, part, Lq, Lk);
    attn_reduce<<<BB*HH*UU, 64, 0, stream>>>(part, mtop, R5, Lq, nslice);
  };

  // ================= encoder =================
  embed_kernel<<<BB*LSQ, 512, 0, stream>>>(x_enc, enc_emb_W, enc_emb_b, R0, LSQ);
  for (int i=0;i<3;i++){
    const float* Wl = enc_attn_W + (size_t)i*4*DD*DD;
    const float* bl = enc_attn_b + (size_t)i*4*DD;
    attention(R0, LSQ, R0, LSQ, Wl, bl, (unsigned)i, true);
    gemm(R5, Wl + 3*DD*DD, bl + 3*DD, R3, BB*LSQ, DD, DD, 0, 0);
    add_ln_kernel<<<BB*LSQ, 128, 0, stream>>>(R0, R3,
        enc_ln_g + (size_t)(i*2+0)*DD, enc_ln_b + (size_t)(i*2+0)*DD, R2);
    gemm(R2, enc_ff_W1 + (size_t)i*DD*DD, enc_ff_b1 + (size_t)i*DD, R4, BB*LSQ, DD, DD, 1, 0);
    gemm(R4, enc_ff_W2 + (size_t)i*DD*DD, enc_ff_b2 + (size_t)i*DD, R5, BB*LSQ, DD, DD, 0, 0);
    add_ln_kernel<<<BB*LSQ, 128, 0, stream>>>(R2, R5,
        enc_ln_g + (size_t)(i*2+1)*DD, enc_ln_b + (size_t)(i*2+1)*DD, R0);
    if (i < 2){
      distil_kernel<<<(BB*LSQ*DD)/256, 256, 0, stream>>>(R0,
          distil_W + (size_t)i*DD*3, distil_b + (size_t)i*DD, R5, LSQ);
      hipMemcpyAsync(R0, R5, (size_t)BB*LSQ*DD*sizeof(float), hipMemcpyDeviceToDevice, stream);
    }
  }
  add_ln_kernel<<<BB*LSQ, 128, 0, stream>>>(R0, nullptr, enc_norm_g, enc_norm_b, R1);

  // ================= decoder =================
  embed_kernel<<<BB*LDQ, 512, 0, stream>>>(x_dec, dec_emb_W, dec_emb_b, R0, LDQ);
  for (int i=0;i<2;i++){
    const float* Wsf = dec_self_W + (size_t)i*4*DD*DD;
    const float* bsf = dec_self_b + (size_t)i*4*DD;
    attention(R0, LDQ, R0, LDQ, Wsf, bsf, (unsigned)(100+2*i), true);
    mix_kernel<<<(BB*LDQ*DD)/256, 256, 0, stream>>>(R5, R2);
    gemm(R2, Wsf + 3*DD*DD, bsf + 3*DD, R3, BB*LDQ, DD, DD, 0, 0);
    add_ln_kernel<<<BB*LDQ, 128, 0, stream>>>(R0, R3,
        dec_ln_g + (size_t)(i*3+0)*DD, dec_ln_b + (size_t)(i*3+0)*DD, R0);
    const float* Wc = dec_cross_W + (size_t)i*4*DD*DD;
    const float* bc = dec_cross_b + (size_t)i*4*DD;
    attention(R0, LDQ, R1, LSQ, Wc, bc, (unsigned)(101+2*i), false);
    gemm(R5, Wc + 3*DD*DD, bc + 3*DD, R3, BB*LDQ, DD, DD, 0, 0);
    add_ln_kernel<<<BB*LDQ, 128, 0, stream>>>(R0, R3,
        dec_ln_g + (size_t)(i*3+1)*DD, dec_ln_b + (size_t)(i*3+1)*DD, R2);
    gemm(R2, dec_ff_W1 + (size_t)i*DD*DD, dec_ff_b1 + (size_t)i*DD, R4, BB*LDQ, DD, DD, 1, 0);
    gemm(R4, dec_ff_W2 + (size_t)i*DD*DD, dec_ff_b2 + (size_t)i*DD, R5, BB*LDQ, DD, DD, 0, 0);
    add_ln_kernel<<<BB*LDQ, 128, 0, stream>>>(R2, R5,
        dec_ln_g + (size_t)(i*3+2)*DD, dec_ln_b + (size_t)(i*3+2)*DD, R0);
  }
  add_ln_kernel<<<BB*LDQ, 128, 0, stream>>>(R0, nullptr, dec_norm_g, dec_norm_b, R2);
  proj_kernel<<<(BB*256)/4, 256, 0, stream>>>(R2, proj_W, proj_b, out);
}

// Round 14
// 2462.008 us; speedup vs baseline: 2.9596x; 1.2045x over previous
//
#include <hip/hip_runtime.h>
#include <cstdio>
#include <cstdint>

// ---------------- constants ----------------
#define BB 8
#define LSQ 1024
#define LDQ 512
#define DD 512
#define HH 8
#define EE 64
#define UU 35            // = 5*ceil(ln(1024)) = 5*ceil(ln(512))
#define RSZF ((size_t)(4u<<20))   // region stride in floats (16 MB)

typedef __attribute__((ext_vector_type(4))) float f32x4;
typedef __attribute__((ext_vector_type(8))) short bfrag; // 8 bf16 in 4 VGPRs
typedef __attribute__((ext_vector_type(4))) unsigned short us4;

__device__ inline unsigned short f2bf(float f){
  union { float f; unsigned u; } v; v.f = f;
  unsigned r = v.u + 0x7fffu + ((v.u >> 16) & 1u);  // RNE
  return (unsigned short)(r >> 16);
}

// ---------------- threefry2x32 (JAX-compatible) ----------------
__host__ __device__ inline unsigned rotl32(unsigned x, int r){ return (x<<r)|(x>>(32-r)); }

__host__ __device__ inline void tf2x32(unsigned k0, unsigned k1, unsigned x0, unsigned x1,
                                       unsigned &o0, unsigned &o1){
  unsigned ks2 = k0 ^ k1 ^ 0x1BD11BDAu;
#define TF_RND(rr) { x0 += x1; x1 = rotl32(x1, rr); x1 ^= x0; }
  x0 += k0; x1 += k1;
  TF_RND(13) TF_RND(15) TF_RND(26) TF_RND(6)
  x0 += k1; x1 += ks2 + 1u;
  TF_RND(17) TF_RND(29) TF_RND(16) TF_RND(24)
  x0 += ks2; x1 += k0 + 2u;
  TF_RND(13) TF_RND(15) TF_RND(26) TF_RND(6)
  x0 += k0; x1 += k1 + 3u;
  TF_RND(17) TF_RND(29) TF_RND(16) TF_RND(24)
  x0 += k1; x1 += ks2 + 4u;
  TF_RND(13) TF_RND(15) TF_RND(26) TF_RND(6)
  x0 += ks2; x1 += k0 + 5u;
#undef TF_RND
  o0 = x0; o1 = x1;
}

__global__ void idx_kernel(unsigned k2a, unsigned k2b, int* __restrict__ idx, int n, int lkMask){
  int i = blockIdx.x*blockDim.x + threadIdx.x;
  if (i >= n) return;
  unsigned o0,o1; tf2x32(k2a, k2b, 0u, (unsigned)i, o0, o1);
  idx[i] = (int)((o0 ^ o1) & (unsigned)lkMask);
}

// ---------------- token conv (wrap pad) + positional embedding ----------------
__global__ __launch_bounds__(512) void embed_kernel(const float* __restrict__ x,
    const float* __restrict__ W, const float* __restrict__ bias,
    float* __restrict__ out, int L){
  int bl = blockIdx.x; int b = bl / L; int l = bl - b*L;
  int d = threadIdx.x;
  __shared__ float xs[3][16];
  if (d < 48){
    int t = d / 16, c = d - t*16;
    int ll = l + t - 1; ll = (ll + L) % L;
    xs[t][c] = x[((size_t)b*L + ll)*16 + c];
  }
  __syncthreads();
  float acc = bias[d];
  const float* w = W + (size_t)d*48;   // W[d][c][t]
  #pragma unroll
  for (int c=0;c<16;c++){
    acc += xs[0][c]*w[c*3+0] + xs[1][c]*w[c*3+1] + xs[2][c]*w[c*3+2];
  }
  int p2 = (d >> 1) * 2;
  float freq = expf((float)p2 * (-(logf(10000.0f)/512.0f)));
  float ang = (float)l * freq;
  acc += (d & 1) ? cosf(ang) : sinf(ang);
  out[((size_t)b*L + l)*DD + d] = acc;
}

// ---------------- MFMA bf16 GEMM: C = A(MxK) * W(NxK)^T + bias ----------------
// 128x128 tile, BK=32, 4 waves each 64x64 (4x4 frags of 16x16x32).
// epi: 0 = plain, 1 = exact GELU, 2 = head-split write (B,H,L,E) with
//      region routing which = n>>9 (stride RSZF) -> supports fused QKV / KV.
__global__ __launch_bounds__(256) void mfma_gemm(const float* __restrict__ A,
    const float* __restrict__ W, const float* __restrict__ bias,
    float* __restrict__ C, int M, int N, int K, int epi, int L){
  __shared__ unsigned short As[128*32];
  __shared__ unsigned short Bs[128*32];
  const int tid = threadIdx.x;
  const int bm = blockIdx.y * 128, bn = blockIdx.x * 128;
  const int wave = tid >> 6, lane = tid & 63;
  const int wm = (wave >> 1) * 64, wn = (wave & 1) * 64;
  f32x4 acc[4][4];
  #pragma unroll
  for (int i=0;i<4;i++)
    #pragma unroll
    for (int j=0;j<4;j++) acc[i][j] = 0.f;

  const int srow = tid >> 3;           // 0..31
  const int scol = (tid & 7) * 4;      // 0,4,...,28
  const int cw  = scol * 2;
  const int cwz = (cw & 8) | ((cw & 48) ^ ((srow & 3) << 4)); // swizzle (row&3 invariant under +32)
  const int frow = lane & 15, fk = (lane >> 4) << 4;

  for (int k0 = 0; k0 < K; k0 += 32){
    f32x4 av[4], wv[4];
    #pragma unroll
    for (int rg=0;rg<4;rg++){
      av[rg] = *(const f32x4*)(A + (size_t)(bm + srow + rg*32)*K + k0 + scol);
      wv[rg] = *(const f32x4*)(W + (size_t)(bn + srow + rg*32)*K + k0 + scol);
    }
    __syncthreads();
    #pragma unroll
    for (int rg=0;rg<4;rg++){
      us4 a4; a4.x=f2bf(av[rg].x); a4.y=f2bf(av[rg].y); a4.z=f2bf(av[rg].z); a4.w=f2bf(av[rg].w);
      us4 b4; b4.x=f2bf(wv[rg].x); b4.y=f2bf(wv[rg].y); b4.z=f2bf(wv[rg].z); b4.w=f2bf(wv[rg].w);
      *(us4*)&As[(srow + rg*32)*32 + (cwz >> 1)] = a4;
      *(us4*)&Bs[(srow + rg*32)*32 + (cwz >> 1)] = b4;
    }
    __syncthreads();
    bfrag af[4], bf[4];
    #pragma unroll
    for (int i=0;i<4;i++){
      int r = wm + i*16 + frow;
      af[i] = *(const bfrag*)&As[r*32 + ((fk ^ ((r & 3) << 4)) >> 1)];
    }
    #pragma unroll
    for (int j=0;j<4;j++){
      int r = wn + j*16 + frow;
      bf[j] = *(const bfrag*)&Bs[r*32 + ((fk ^ ((r & 3) << 4)) >> 1)];
    }
    #pragma unroll
    for (int i=0;i<4;i++)
      #pragma unroll
      for (int j=0;j<4;j++)
        acc[i][j] = __builtin_amdgcn_mfma_f32_16x16x32_bf16(af[i], bf[j], acc[i][j], 0, 0, 0);
  }

  #pragma unroll
  for (int j=0;j<4;j++){
    int n = bn + wn + j*16 + (lane & 15);
    float bs = bias[n];
    #pragma unroll
    for (int i=0;i<4;i++){
      #pragma unroll
      for (int q=0;q<4;q++){
        int m = bm + wm + i*16 + (lane >> 4)*4 + q;
        float v = acc[i][j][q] + bs;
        if (epi == 1) v = 0.5f*v*(1.0f+erff(v*0.70710678118654752f));
        if (epi == 2){
          int b = m / L, l = m - b*L;
          int which = n >> 9;               // region (q/k/v)
          int h = (n >> 6) & 7, e = n & 63;
          C[(size_t)which*RSZF + (((size_t)(b*HH + h))*L + l)*EE + e] = v;
        } else {
          C[(size_t)m*N + n] = v;
        }
      }
    }
  }
}

// ---------------- residual add + LayerNorm (y may be null) ----------------
__global__ __launch_bounds__(128) void add_ln_kernel(const float* __restrict__ x,
    const float* __restrict__ y, const float* __restrict__ g,
    const float* __restrict__ bb, float* __restrict__ out){
  const int row = blockIdx.x, t = threadIdx.x;
  float4 v = *(const float4*)(x + (size_t)row*DD + t*4);
  if (y){
    float4 w = *(const float4*)(y + (size_t)row*DD + t*4);
    v.x+=w.x; v.y+=w.y; v.z+=w.z; v.w+=w.w;
  }
  __shared__ float red[128];
  red[t] = v.x+v.y+v.z+v.w; __syncthreads();
  for (int o=64;o>0;o>>=1){ if (t<o) red[t]+=red[t+o]; __syncthreads(); }
  float mean = red[0] * (1.0f/512.0f);
  __syncthreads();
  float dx=v.x-mean, dy=v.y-mean, dz=v.z-mean, dw=v.w-mean;
  red[t] = dx*dx+dy*dy+dz*dz+dw*dw; __syncthreads();
  for (int o=64;o>0;o>>=1){ if (t<o) red[t]+=red[t+o]; __syncthreads(); }
  float rs = rsqrtf(red[0]*(1.0f/512.0f) + 1e-5f);
  float4 gg  = *(const float4*)(g  + t*4);
  float4 bv  = *(const float4*)(bb + t*4);
  float4 o4;
  o4.x = dx*rs*gg.x + bv.x;
  o4.y = dy*rs*gg.y + bv.y;
  o4.z = dz*rs*gg.z + bv.z;
  o4.w = dw*rs*gg.w + bv.w;
  *(float4*)(out + (size_t)row*DD + t*4) = o4;
}

// ---------------- depthwise distil conv (zero pad) ----------------
__global__ void distil_kernel(const float* __restrict__ x, const float* __restrict__ w,
    const float* __restrict__ bias, float* __restrict__ out, int L){
  size_t gid = (size_t)blockIdx.x*blockDim.x + threadIdx.x;
  int d = gid & (DD-1);
  size_t bl = gid >> 9;
  int l = (int)(bl % L); int b = (int)(bl / L);
  float acc = bias[d];
  const float* wd = w + (size_t)d*3;
  if (l > 0)     acc += x[(((size_t)b*L + l-1)*DD) + d] * wd[0];
  acc +=           x[(((size_t)b*L + l  )*DD) + d] * wd[1];
  if (l < L-1)   acc += x[(((size_t)b*L + l+1)*DD) + d] * wd[2];
  out[gid] = acc;
}

// ---------------- sampled-score: 8 queries/wave, 8 lanes/query, 2-deep prefetch ----
// lane = ql*8 + eg; query qglob = wid*8 + ql owns dims [eg*8, eg*8+8).
__global__ __launch_bounds__(256) void sampleM_wave(const float* __restrict__ q,
    const float* __restrict__ k, const int* __restrict__ idx,
    float* __restrict__ M, int lqShift, int Lk){
  int wid = (int)((blockIdx.x*(size_t)blockDim.x + threadIdx.x) >> 6);
  int lane = threadIdx.x & 63;
  int ql = lane >> 3, eg = lane & 7;
  int qglob = wid*8 + ql;                    // = bh*Lq + l
  int l  = qglob & ((1 << lqShift) - 1);
  const int bh = qglob >> lqShift;
  const float4* qp = (const float4*)(q + ((size_t)qglob << 6) + eg*8);
  float4 q0 = qp[0], q1 = qp[1];
  const float* kbase = k + ((size_t)bh*Lk)*EE + eg*8;
  const int* ip = idx + l*UU;

  int ki0 = ip[0];
  const f32x4* kp = (const f32x4*)(kbase + (size_t)ki0*EE);
  f32x4 k0 = kp[0], k1 = kp[1];
  int kin = ip[1];                            // idx prefetched 1 ahead of K

  float mx = -3.0e38f, sm = 0.f;
  for (int j = 0; j < UU; ++j){
    f32x4 c0 = k0, c1 = k1;
    int kin2 = (j + 2 < UU) ? ip[j + 2] : 0;  // idx 2 ahead
    if (j + 1 < UU){
      const f32x4* kpn = (const f32x4*)(kbase + (size_t)kin*EE);
      k0 = kpn[0]; k1 = kpn[1];               // K 1 ahead
    }
    kin = kin2;
    float p = q0.x*c0.x + q0.y*c0.y + q0.z*c0.z + q0.w*c0.w
            + q1.x*c1.x + q1.y*c1.y + q1.z*c1.z + q1.w*c1.w;
    p += __shfl_xor(p, 1);
    p += __shfl_xor(p, 2);
    p += __shfl_xor(p, 4);
    mx = fmaxf(mx, p); sm += p;
  }
  if (eg == 0) M[qglob] = mx - sm/(float)Lk;
}

// ---------------- stable top-k (u=35), register-resident ----------------
__global__ __launch_bounds__(256) void topk_kernel(const float* __restrict__ M,
    int* __restrict__ mtop, int Lq){
  int bh = blockIdx.x, t = threadIdx.x;
  const float* m = M + (size_t)bh*Lq;
  const int nv = Lq >> 8;       // 4 (enc) or 2 (dec)
  float v[4]; int vi[4];
  for (int i=0;i<nv;i++){ vi[i] = t + (i<<8); v[i] = m[vi[i]]; }
  __shared__ float wv_s[4]; __shared__ int wi_s[4]; __shared__ int winner;
  for (int pass=0; pass<UU; ++pass){
    float best = v[0]; int bi = vi[0];
    for (int i=1;i<nv;i++) if (v[i] > best || (v[i] == best && vi[i] < bi)){ best=v[i]; bi=vi[i]; }
    #pragma unroll
    for (int o=32;o>0;o>>=1){
      float ov = __shfl_xor(best, o); int oi = __shfl_xor(bi, o);
      if (ov > best || (ov == best && oi < bi)){ best=ov; bi=oi; }
    }
    if ((t & 63) == 0){ wv_s[t>>6] = best; wi_s[t>>6] = bi; }
    __syncthreads();
    if (t == 0){
      float bb2 = wv_s[0]; int bbi = wi_s[0];
      for (int w2=1;w2<4;w2++)
        if (wv_s[w2] > bb2 || (wv_s[w2] == bb2 && wi_s[w2] < bbi)){ bb2=wv_s[w2]; bbi=wi_s[w2]; }
      if ((unsigned)bbi >= (unsigned)Lq) bbi = 0;   // NaN-safety
      mtop[bh*UU + pass] = bbi; winner = bbi;
    }
    __syncthreads();
    for (int i=0;i<nv;i++) if (vi[i] == winner) v[i] = -3.4e38f;
  }
}

// ---------------- V mean over keys (16-way row-parallel) ----------------
__global__ __launch_bounds__(1024) void vmean_kernel(const float* __restrict__ v,
    float* __restrict__ vm, int Lk){
  int bh = blockIdx.x; int t = threadIdx.x;
  int e = t & 63, g = t >> 6;   // 16 groups
  float s = 0.f;
  for (int r = g; r < Lk; r += 16) s += v[((size_t)bh*Lk + r)*EE + e];
  __shared__ float red[16][64];
  red[g][e] = s; __syncthreads();
  if (g < 8) red[g][e] += red[g+8][e];
  __syncthreads();
  if (g < 4) red[g][e] += red[g+4][e];
  __syncthreads();
  if (g < 2) red[g][e] += red[g+2][e];
  __syncthreads();
  if (g == 0) vm[bh*EE + e] = (red[0][e] + red[1][e]) / (float)Lk;
}

// ---------------- broadcast mean(V) into ctx (B,Lq,H,E) ----------------
__global__ __launch_bounds__(512) void fill_ctx_kernel(const float* __restrict__ vm,
    float* __restrict__ ctx, int Lq){
  int bl = blockIdx.x; int b = bl / Lq;
  int c = threadIdx.x;
  ctx[(size_t)bl*DD + c] = vm[(b*HH + (c>>6))*EE + (c & 63)];
}

// ---------------- split-K attention, phase 1: per-slice partials ----------------
// grid (nslice, BB*HH); each block handles 64 keys for all 35 rows.
// part[bh][slice][r][66] = { acc[64], m, s }
__global__ __launch_bounds__(256) void attn_part(const float* __restrict__ q,
    const float* __restrict__ k, const float* __restrict__ v,
    const int* __restrict__ mtop, float* __restrict__ part, int Lq, int Lk){
  const int slice = blockIdx.x, bh = blockIdx.y, nslice = gridDim.x;
  const int t = threadIdx.x, lane = t & 63, g = t >> 6;
  const int kc = slice * 64;
  __shared__ float Qs[UU][EE];
  __shared__ float KT[EE][65];
  __shared__ float Vs[64][68];
  __shared__ float Ps[UU][64];
  __shared__ int rows_s[UU];
  if (t < UU) rows_s[t] = mtop[bh*UU + t];
  __syncthreads();
  for (int r = g; r < UU; r += 4)
    Qs[r][lane] = q[((size_t)bh*Lq + rows_s[r])*EE + lane];
  const int kr = t >> 2, c0 = (t & 3) * 16;
  const float* krow = k + ((size_t)bh*Lk + kc + kr)*EE + c0;
  const float* vrow = v + ((size_t)bh*Lk + kc + kr)*EE + c0;
  #pragma unroll
  for (int i2=0;i2<4;i2++){
    float4 kv = *(const float4*)(krow + i2*4);
    KT[c0+i2*4+0][kr] = kv.x; KT[c0+i2*4+1][kr] = kv.y;
    KT[c0+i2*4+2][kr] = kv.z; KT[c0+i2*4+3][kr] = kv.w;
    *(float4*)&Vs[kr][c0 + i2*4] = *(const float4*)(vrow + i2*4);
  }
  __syncthreads();
  float* pb = part + (((size_t)bh*nslice + slice)*UU)*66;
  #pragma unroll
  for (int s=0;s<9;s++){
    int r = g + 4*s; if (r >= UU) break;
    float sc = 0.f;
    #pragma unroll
    for (int d=0; d<EE; d++) sc += Qs[r][d] * KT[d][lane];
    sc *= 0.125f;
    float cm = sc;
    #pragma unroll
    for (int o=32;o>0;o>>=1) cm = fmaxf(cm, __shfl_xor(cm, o));
    float p = expf(sc - cm);
    float ps = p;
    #pragma unroll
    for (int o=32;o>0;o>>=1) ps += __shfl_xor(ps, o);
    Ps[r][lane] = p;
    if (lane == 0){ pb[r*66 + 64] = cm; pb[r*66 + 65] = ps; }
  }
  __syncthreads();
  #pragma unroll
  for (int s=0;s<9;s++){
    int r = g + 4*s; if (r >= UU) break;
    float a = 0.f;
    #pragma unroll
    for (int c=0;c<64;c++) a += Ps[r][c] * Vs[c][lane];
    pb[r*66 + lane] = a;
  }
}

// ---------------- split-K attention, phase 2: merge slices ----------------
__global__ __launch_bounds__(64) void attn_reduce(const float* __restrict__ part,
    const int* __restrict__ mtop, float* __restrict__ ctx, int Lq, int nslice){
  int blk = blockIdx.x; int r = blk % UU; int bh = blk / UU;
  int h = bh & 7, b = bh >> 3;
  int lane = threadIdx.x;
  const float* pb = part + ((size_t)bh*nslice*UU + r)*66;
  float mg = -3.0e38f;
  for (int i=0;i<nslice;i++) mg = fmaxf(mg, pb[(size_t)i*UU*66 + 64]);
  float acc = 0.f, den = 0.f;
  for (int i=0;i<nslice;i++){
    float sc = expf(pb[(size_t)i*UU*66 + 64] - mg);
    acc += sc * pb[(size_t)i*UU*66 + lane];
    den += sc * pb[(size_t)i*UU*66 + 65];
  }
  int row = mtop[bh*UU + r];
  ctx[(((size_t)b*Lq + row)*HH + h)*EE + lane] = acc/den;
}

// ---------------- decoder self-attn "mix" permute ----------------
__global__ void mix_kernel(const float* __restrict__ ctx, float* __restrict__ out){
  size_t gid = (size_t)blockIdx.x*blockDim.x + threadIdx.x; // B*512*512
  int b = (int)(gid >> 18);
  int f = (int)(gid & 262143);
  int hh = f >> 15;
  int rem = f & 32767;
  int l = rem >> 6, e = rem & 63;
  out[gid] = ctx[(((size_t)b*LDQ + l)*HH + hh)*EE + e];
}

// ---------------- final projection, last PRED_LEN rows ----------------
__global__ __launch_bounds__(256) void proj_kernel(const float* __restrict__ dec,
    const float* __restrict__ pW, const float* __restrict__ pb, float* __restrict__ out){
  int r = blockIdx.x*4 + (threadIdx.x >> 6);   // 2048 outputs
  int lane = threadIdx.x & 63;
  int b = r >> 8, pp = r & 255;
  const float* drow = dec + (((size_t)b*LDQ) + 256 + pp)*DD;
  float s = 0.f;
  for (int e2 = lane; e2 < DD; e2 += 64) s += drow[e2]*pW[e2];
  for (int o=32;o>0;o>>=1) s += __shfl_down(s, o);
  if (lane == 0) out[r] = s + pb[0];
}

// ---------------- host orchestration ----------------
extern "C" void kernel_launch(void* const* d_in, const int* in_sizes, int n_in,
                              void* d_out, int out_size, void* d_ws, size_t ws_size,
                              hipStream_t stream){
  const float* x_enc     = (const float*)d_in[0];
  const float* x_dec     = (const float*)d_in[1];
  const float* enc_emb_W = (const float*)d_in[2];
  const float* enc_emb_b = (const float*)d_in[3];
  const float* dec_emb_W = (const float*)d_in[4];
  const float* dec_emb_b = (const float*)d_in[5];
  const float* enc_attn_W= (const float*)d_in[6];
  const float* enc_attn_b= (const float*)d_in[7];
  const float* enc_ff_W1 = (const float*)d_in[8];
  const float* enc_ff_b1 = (const float*)d_in[9];
  const float* enc_ff_W2 = (const float*)d_in[10];
  const float* enc_ff_b2 = (const float*)d_in[11];
  const float* enc_ln_g  = (const float*)d_in[12];
  const float* enc_ln_b  = (const float*)d_in[13];
  const float* distil_W  = (const float*)d_in[14];
  const float* distil_b  = (const float*)d_in[15];
  const float* enc_norm_g= (const float*)d_in[16];
  const float* enc_norm_b= (const float*)d_in[17];
  const float* dec_self_W= (const float*)d_in[18];
  const float* dec_self_b= (const float*)d_in[19];
  const float* dec_cross_W=(const float*)d_in[20];
  const float* dec_cross_b=(const float*)d_in[21];
  const float* dec_ff_W1 = (const float*)d_in[22];
  const float* dec_ff_b1 = (const float*)d_in[23];
  const float* dec_ff_W2 = (const float*)d_in[24];
  const float* dec_ff_b2 = (const float*)d_in[25];
  const float* dec_ln_g  = (const float*)d_in[26];
  const float* dec_ln_b  = (const float*)d_in[27];
  const float* dec_norm_g= (const float*)d_in[28];
  const float* dec_norm_b= (const float*)d_in[29];
  const float* proj_W    = (const float*)d_in[30];
  const float* proj_b    = (const float*)d_in[31];
  float* out = (float*)d_out;

  float* ws = (float*)d_ws;
  float* R0 = ws;            // enc state / dec state
  float* R1 = ws + 1*RSZF;   // enc final (kept for cross-attn)
  float* R2 = ws + 2*RSZF;   // q
  float* R3 = ws + 3*RSZF;   // k   (R2+RSZF — fused QKV routing relies on this)
  float* R4 = ws + 4*RSZF;   // v
  float* R5 = ws + 5*RSZF;   // ctx / ffn temps
  float* Mbuf  = ws + 6*RSZF;            // 65536
  float* vmean = Mbuf + BB*HH*1024;      // 4096
  float* part  = vmean + BB*HH*EE;       // 64*16*35*66 = 2,365,440 floats
  int*   idxb  = (int*)(part + (size_t)BB*HH*16*UU*66);
  int*   mtop  = idxb + 1024*UU;
  size_t needed = ((size_t)(6*RSZF) + BB*HH*1024 + BB*HH*EE + (size_t)BB*HH*16*UU*66)*4
                + (1024*UU + BB*HH*UU)*4;
  if (ws_size < needed){
    fprintf(stderr, "kernel_launch: ws too small (%zu < %zu)\n", ws_size, needed);
    return;
  }

  auto gemm = [&](const float* A, const float* W, const float* bias, float* C,
                  int M, int N, int K, int epi, int L){
    dim3 g(N/128, M/128);
    mfma_gemm<<<g, 256, 0, stream>>>(A, W, bias, C, M, N, K, epi, L);
  };

  auto attention = [&](const float* qin, int Lq, const float* kvin, int Lk,
                       const float* Wm, const float* bm, unsigned foldc, bool self){
    if (self){
      gemm(qin, Wm, bm, R2, BB*Lq, 3*DD, DD, 2, Lq);          // fused q,k,v -> R2,R3,R4
    } else {
      gemm(qin,  Wm + 0*DD*DD, bm + 0*DD, R2, BB*Lq, DD, DD, 2, Lq);
      gemm(kvin, Wm + 1*DD*DD, bm + 1*DD, R3, BB*Lk, 2*DD, DD, 2, Lk); // fused k,v -> R3,R4
    }
    unsigned fk0, fk1, k2a, k2b;
    tf2x32(0u, 1234u, 0u, foldc, fk0, fk1);
    tf2x32(fk0, fk1, 0u, 1u, k2a, k2b);
    int n = Lq * UU;
    idx_kernel<<<(n+255)/256, 256, 0, stream>>>(k2a, k2b, idxb, n, Lk-1);
    int lqShift = (Lq == 1024) ? 10 : 9;
    int nthreads = BB*HH*Lq*8;   // 8 lanes per query
    sampleM_wave<<<nthreads/256, 256, 0, stream>>>(R2, R3, idxb, Mbuf, lqShift, Lk);
    topk_kernel<<<BB*HH, 256, 0, stream>>>(Mbuf, mtop, Lq);
    vmean_kernel<<<BB*HH, 1024, 0, stream>>>(R4, vmean, Lk);
    fill_ctx_kernel<<<BB*Lq, 512, 0, stream>>>(vmean, R5, Lq);
    int nslice = Lk / 64;
    attn_part<<<dim3(nslice, BB*HH), 256, 0, stream>>>(R2, R3, R4, mtop, part, Lq, Lk);
    attn_reduce<<<BB*HH*UU, 64, 0, stream>>>(part, mtop, R5, Lq, nslice);
  };

  // ================= encoder =================
  embed_kernel<<<BB*LSQ, 512, 0, stream>>>(x_enc, enc_emb_W, enc_emb_b, R0, LSQ);
  for (int i=0;i<3;i++){
    const float* Wl = enc_attn_W + (size_t)i*4*DD*DD;
    const float* bl = enc_attn_b + (size_t)i*4*DD;
    attention(R0, LSQ, R0, LSQ, Wl, bl, (unsigned)i, true);
    gemm(R5, Wl + 3*DD*DD, bl + 3*DD, R3, BB*LSQ, DD, DD, 0, 0);
    add_ln_kernel<<<BB*LSQ, 128, 0, stream>>>(R0, R3,
        enc_ln_g + (size_t)(i*2+0)*DD, enc_ln_b + (size_t)(i*2+0)*DD, R2);
    gemm(R2, enc_ff_W1 + (size_t)i*DD*DD, enc_ff_b1 + (size_t)i*DD, R4, BB*LSQ, DD, DD, 1, 0);
    gemm(R4, enc_ff_W2 + (size_t)i*DD*DD, enc_ff_b2 + (size_t)i*DD, R5, BB*LSQ, DD, DD, 0, 0);
    add_ln_kernel<<<BB*LSQ, 128, 0, stream>>>(R2, R5,
        enc_ln_g + (size_t)(i*2+1)*DD, enc_ln_b + (size_t)(i*2+1)*DD, R0);
    if (i < 2){
      distil_kernel<<<(BB*LSQ*DD)/256, 256, 0, stream>>>(R0,
          distil_W + (size_t)i*DD*3, distil_b + (size_t)i*DD, R5, LSQ);
      hipMemcpyAsync(R0, R5, (size_t)BB*LSQ*DD*sizeof(float), hipMemcpyDeviceToDevice, stream);
    }
  }
  add_ln_kernel<<<BB*LSQ, 128, 0, stream>>>(R0, nullptr, enc_norm_g, enc_norm_b, R1);

  // ================= decoder =================
  embed_kernel<<<BB*LDQ, 512, 0, stream>>>(x_dec, dec_emb_W, dec_emb_b, R0, LDQ);
  for (int i=0;i<2;i++){
    const float* Wsf = dec_self_W + (size_t)i*4*DD*DD;
    const float* bsf = dec_self_b + (size_t)i*4*DD;
    attention(R0, LDQ, R0, LDQ, Wsf, bsf, (unsigned)(100+2*i), true);
    mix_kernel<<<(BB*LDQ*DD)/256, 256, 0, stream>>>(R5, R2);
    gemm(R2, Wsf + 3*DD*DD, bsf + 3*DD, R3, BB*LDQ, DD, DD, 0, 0);
    add_ln_kernel<<<BB*LDQ, 128, 0, stream>>>(R0, R3,
        dec_ln_g + (size_t)(i*3+0)*DD, dec_ln_b + (size_t)(i*3+0)*DD, R0);
    const float* Wc = dec_cross_W + (size_t)i*4*DD*DD;
    const float* bc = dec_cross_b + (size_t)i*4*DD;
    attention(R0, LDQ, R1, LSQ, Wc, bc, (unsigned)(101+2*i), false);
    gemm(R5, Wc + 3*DD*DD, bc + 3*DD, R3, BB*LDQ, DD, DD, 0, 0);
    add_ln_kernel<<<BB*LDQ, 128, 0, stream>>>(R0, R3,
        dec_ln_g + (size_t)(i*3+1)*DD, dec_ln_b + (size_t)(i*3+1)*DD, R2);
    gemm(R2, dec_ff_W1 + (size_t)i*DD*DD, dec_ff_b1 + (size_t)i*DD, R4, BB*LDQ, DD, DD, 1, 0);
    gemm(R4, dec_ff_W2 + (size_t)i*DD*DD, dec_ff_b2 + (size_t)i*DD, R5, BB*LDQ, DD, DD, 0, 0);
    add_ln_kernel<<<BB*LDQ, 128, 0, stream>>>(R2, R5,
        dec_ln_g + (size_t)(i*3+2)*DD, dec_ln_b + (size_t)(i*3+2)*DD, R0);
  }
  add_ln_kernel<<<BB*LDQ, 128, 0, stream>>>(R0, nullptr, dec_norm_g, dec_norm_b, R2);
  proj_kernel<<<(BB*256)/4, 256, 0, stream>>>(R2, proj_W, proj_b, out);
}